// Round 9
// baseline (275.588 us; speedup 1.0000x reference)
//
#include <hip/hip_runtime.h>
#include <math.h>

// ---------------- problem constants ----------------
#define TTD 1024
#define DDM 1024
#define HDIM 64
#define NOUTW 4096
#define PSCALE 0.125f
#define LS 72   // padded LDS stride (non-flash kernels)

typedef __attribute__((ext_vector_type(8))) __bf16 bf16x8;
typedef __attribute__((ext_vector_type(4))) float f32x4;
#define MFMA16(a,b,c) __builtin_amdgcn_mfma_f32_16x16x32_bf16(a,b,c,0,0,0)

__device__ __forceinline__ ushort f2b(float f) {
  unsigned u = __builtin_bit_cast(unsigned, f);
  return (ushort)((u + 0x7fffu + ((u >> 16) & 1u)) >> 16);
}
__device__ __forceinline__ float b2f(ushort u) {
  unsigned v = (unsigned)u << 16;
  return __builtin_bit_cast(float, v);
}

__device__ __forceinline__ void gload_lds16(const ushort* g, ushort* l) {
  __builtin_amdgcn_global_load_lds(
      (const __attribute__((address_space(1))) unsigned*)g,
      (__attribute__((address_space(3))) unsigned*)l, 16, 0, 0);
}

// XOR-swizzled 64x64 bf16 tile: 16B slot index for (row, chunk)
#define SWZ(row, cc) (((row) * 8 + ((cc) ^ ((row) & 7))) * 8)

// async-stage one 64x64 tile (rows at gs-elem stride) into swizzled LDS tile
__device__ __forceinline__ void stage_tile(const ushort* gb, long gs, ushort* tile,
                                           int w, int l) {
  int sub = l >> 3, cc = (l & 7) ^ sub;
  #pragma unroll
  for (int it = 0; it < 2; ++it) {
    int q = w * 2 + it;
    gload_lds16(gb + (long)(q * 8 + sub) * gs + cc * 8, &tile[(q * 64 + l) * 8]);
  }
}

__device__ __forceinline__ bf16x8 frag(const ushort* tile, int row, int cc) {
  return *(const bf16x8*)&tile[SWZ(row, cc)];
}

// ---------------- workspace layout (bytes); total = 149,291,008 (proven) ----------------
#define OFF_X     0L            // X bf16 [32][1024 j][1024 t] : 64 MiB
#define OFF_PZ    67108864L     // KZ bf16 [32][15][1024 j][64 d] : 60 MiB (K - prefix)
// aliases inside PZ (all dead before solveB writes KZ):
#define OFF_HSB   67108864L
#define OFF_QWW   69206016L
#define OFF_KWW   71303168L
#define OFF_VWW   73400320L
#define OFF_W2B   75497472L
#define OFF_WLOWB 75759616L
#define OFF_WRAW  83886080L     // fp32 1024x4096, dead after convdir
#define OFF_TB    130023424L    // Tbeta bf16 (solveA->solveB); dead after solveB
#define OFF_OALL  130023424L    // o_all bf16 overlays TB (flash writes after solveB)
#define OFF_YB    134217728L    // Yb bf16 (solveA->solveB); ow_b overlays after solveB
#define OFF_OWB   134217728L
#define OFF_WHB   138412032L    // wh bf16 (live through flash)
#define OFF_QB    142606336L
#define OFF_KB    144703488L
#define OFF_VTB   146800640L
#define OFF_BETA  148897792L
#define OFF_BW64  149159936L    // 64x1024 bf16 [bt_w ; w1]

// ---------------- fp32 -> bf16 convert (generic) ----------------
__global__ __launch_bounds__(256) void cvt_kernel(const float* __restrict__ x,
                                                  ushort* __restrict__ y, long n) {
  long i = ((long)blockIdx.x * 256 + threadIdx.x) * 4;
  if (i >= n) return;
  float4 f = *(const float4*)(x + i);
  ushort4 o;
  o.x = f2b(f.x); o.y = f2b(f.y); o.z = f2b(f.z); o.w = f2b(f.w);
  *(ushort4*)(y + i) = o;
}

// ---------------- merged fp32 -> bf16 convert (7 segments, one launch) ----------------
struct CvtSegs {
  const float* src[7];
  ushort* dst[7];
  long cnt[7];
};
__global__ __launch_bounds__(256) void cvt_all_kernel(CvtSegs sg) {
  long e = ((long)blockIdx.x * 256 + threadIdx.x) * 4;
  #pragma unroll
  for (int s = 0; s < 7; ++s) {
    if (e < sg.cnt[s]) {
      float4 f = *(const float4*)(sg.src[s] + e);
      ushort4 o;
      o.x = f2b(f.x); o.y = f2b(f.y); o.z = f2b(f.z); o.w = f2b(f.w);
      *(ushort4*)(sg.dst[s] + e) = o;
      return;
    }
    e -= sg.cnt[s];
  }
}

// ---------------- fused QKV projections: async dbuf swizzled, 1 barrier/K64 ----------------
__global__ __launch_bounds__(256) void qkv_kernel(
    const ushort* __restrict__ hsb,
    const ushort* __restrict__ wq, const ushort* __restrict__ wk, const ushort* __restrict__ wv,
    ushort* __restrict__ cq, ushort* __restrict__ ck, ushort* __restrict__ cv)
{
  int z = blockIdx.z;
  const ushort* B = (z == 0) ? wq : (z == 1) ? wk : wv;
  __shared__ ushort Ab[2][4096];
  __shared__ ushort Bb[2][4096];
  int tid = threadIdx.x, w = tid >> 6, l = tid & 63;
  int quad = l >> 4, lane15 = l & 15;
  int rm = blockIdx.y * 64, cn = blockIdx.x * 64;
  const ushort* Ag = hsb + (long)rm * DDM;
  const ushort* Bg = B + (long)cn * DDM;

  stage_tile(Ag, DDM, &Ab[0][0], w, l);
  stage_tile(Bg, DDM, &Bb[0][0], w, l);
  __syncthreads();

  f32x4 acc[4] = {};
  int cur = 0;
  for (int kt = 0; kt < 16; ++kt) {
    if (kt < 15) {
      stage_tile(Ag + (kt + 1) * 64, DDM, &Ab[cur ^ 1][0], w, l);
      stage_tile(Bg + (kt + 1) * 64, DDM, &Bb[cur ^ 1][0], w, l);
    }
    #pragma unroll
    for (int s = 0; s < 2; ++s) {
      bf16x8 af = frag(&Ab[cur][0], w * 16 + lane15, s * 4 + quad);
      #pragma unroll
      for (int f = 0; f < 4; ++f)
        acc[f] = MFMA16(af, frag(&Bb[cur][0], f * 16 + lane15, s * 4 + quad), acc[f]);
    }
    __syncthreads();
    cur ^= 1;
  }
  int orow = rm + w * 16 + quad * 4;
  if (z < 2) {
    ushort* Cb = (z == 0) ? cq : ck;
    #pragma unroll
    for (int f = 0; f < 4; ++f)
      #pragma unroll
      for (int r = 0; r < 4; ++r)
        Cb[(long)(orow + r) * DDM + cn + f * 16 + lane15] = f2b(acc[f][r]);
  } else {
    #pragma unroll
    for (int f = 0; f < 4; ++f) {
      ushort4 o;
      o.x = f2b(acc[f][0]); o.y = f2b(acc[f][1]);
      o.z = f2b(acc[f][2]); o.w = f2b(acc[f][3]);
      *(uint4*)&cv[(long)(cn + f * 16 + lane15) * TTD + orow] = *(const uint4*)&o;
    }
  }
}

// ---------------- w_raw GEMM (K=32): w_raw = w_low @ w2^T, fp32 out ----------------
__global__ __launch_bounds__(256) void wraw_kernel(
    const ushort* __restrict__ A, const ushort* __restrict__ B, float* __restrict__ C)
{
  __shared__ ushort As[64 * 32];
  __shared__ ushort Bs[64 * 32];
  int tid = threadIdx.x, w = tid >> 6, l = tid & 63;
  int quad = l >> 4, lane15 = l & 15;
  int rm = blockIdx.y * 64, cn = blockIdx.x * 64;
  int row = tid >> 2, ch = (tid & 3) * 8;
  f32x4 acc[4] = {};
  gload_lds16(A + (long)(rm + row) * 32 + ch, &As[tid * 8]);
  gload_lds16(B + (long)(cn + row) * 32 + ch, &Bs[tid * 8]);
  __syncthreads();
  bf16x8 af = *(const bf16x8*)&As[(w * 16 + lane15) * 32 + quad * 8];
  #pragma unroll
  for (int f = 0; f < 4; ++f) {
    bf16x8 bf = *(const bf16x8*)&Bs[(f * 16 + lane15) * 32 + quad * 8];
    acc[f] = MFMA16(af, bf, acc[f]);
  }
  int orow = rm + w * 16 + quad * 4;
  #pragma unroll
  for (int f = 0; f < 4; ++f)
    #pragma unroll
    for (int r = 0; r < 4; ++r)
      C[(long)(orow + r) * NOUTW + cn + f * 16 + lane15] = acc[f][r];
}

// ---------------- small projections + fused beta: bt/w1 stacked weights ----------------
__global__ __launch_bounds__(256) void smallproj_kernel(
    const ushort* __restrict__ hsb, const ushort* __restrict__ bw,
    const float* __restrict__ bt_b, float* __restrict__ beta,
    ushort* __restrict__ wlowb)
{
  int rm = blockIdx.x * 64;
  int tid = threadIdx.x, w = tid >> 6, l = tid & 63;
  int quad = l >> 4, lane15 = l & 15;
  f32x4 acc[4] = {};
  for (int k0 = 0; k0 < 1024; k0 += 32) {
    bf16x8 af = *(const bf16x8*)&hsb[(long)(rm + w * 16 + lane15) * 1024 + k0 + quad * 8];
    #pragma unroll
    for (int f = 0; f < 4; ++f) {
      bf16x8 bf = *(const bf16x8*)&bw[(long)(f * 16 + lane15) * 1024 + k0 + quad * 8];
      acc[f] = MFMA16(af, bf, acc[f]);
    }
  }
  int orow = rm + w * 16 + quad * 4;
  #pragma unroll
  for (int f = 0; f < 2; ++f) {
    int hr = f * 16 + lane15;
    float bb = bt_b[hr];
    #pragma unroll
    for (int r = 0; r < 4; ++r)
      beta[(long)hr * TTD + orow + r] = 2.f / (1.f + expf(-(acc[f][r] + bb)));
  }
  #pragma unroll
  for (int f = 2; f < 4; ++f)
    #pragma unroll
    for (int r = 0; r < 4; ++r)
      wlowb[(long)(orow + r) * 32 + (f - 2) * 16 + lane15] = f2b(acc[f][r]);
}

// ---------------- solveA: Tbeta = (I+Lm)^-1 diag(beta), Yb = Tbeta.wh ----------------
__global__ __launch_bounds__(256) void solveA_kernel(
    const ushort* __restrict__ whb, const float* __restrict__ beta,
    ushort* __restrict__ TB, ushort* __restrict__ YB)
{
  int c = blockIdx.x, h = blockIdx.y;
  const ushort* whc = whb + ((long)h * TTD + c * 64) * HDIM;
  const float* bet = beta + (long)h * TTD + c * 64;
  ushort* TBh = TB + ((long)h * 16 + c) * 4096;
  ushort* YBh = YB + ((long)h * 16 + c) * 4096;

  __shared__ float Lm[64][65];
  __shared__ float Vf[64][65];
  __shared__ ushort WT[64 * LS];
  __shared__ ushort Tb[64 * LS];

  int tid = threadIdx.x, w = tid >> 6, l = tid & 63;
  int quad = l >> 4, lane15 = l & 15;

  f32x4 g[4] = {};
  #pragma unroll
  for (int s = 0; s < 2; ++s) {
    bf16x8 af = *(const bf16x8*)&whc[(long)(w * 16 + lane15) * HDIM + s * 32 + quad * 8];
    #pragma unroll
    for (int f = 0; f < 4; ++f) {
      bf16x8 bf = *(const bf16x8*)&whc[(long)(f * 16 + lane15) * HDIM + s * 32 + quad * 8];
      g[f] = MFMA16(af, bf, g[f]);
    }
  }
  #pragma unroll
  for (int r = 0; r < 4; ++r) {
    int t = w * 16 + quad * 4 + r;
    float bv = bet[t];
    #pragma unroll
    for (int f = 0; f < 4; ++f) {
      int tp = f * 16 + lane15;
      Lm[t][tp] = (t > tp) ? bv * g[f][r] : 0.f;
    }
  }
  {
    int d0 = (tid & 7) * 8;
    #pragma unroll
    for (int it = 0; it < 2; ++it) {
      int t = it * 32 + (tid >> 3);
      uint4 pk = *(const uint4*)&whc[(long)t * HDIM + d0];
      const ushort* pu = (const ushort*)&pk;
      #pragma unroll
      for (int i = 0; i < 8; ++i) WT[(d0 + i) * LS + t] = pu[i];
    }
  }
  __syncthreads();

  {
    float cur[16];
    #pragma unroll
    for (int i = 0; i < 16; ++i) cur[i] = (w * 16 + i == l) ? bet[l] : 0.f;
    for (int sb = 0; sb < 4; ++sb) {
      if (w == sb) {
        float xloc[16];
        #pragma unroll
        for (int i = 0; i < 16; ++i) {
          float bv = cur[i];
          #pragma unroll
          for (int j2 = 0; j2 < 16; ++j2)
            if (j2 < i) bv -= Lm[sb * 16 + i][sb * 16 + j2] * xloc[j2];
          xloc[i] = bv;
          Vf[sb * 16 + i][l] = bv;
        }
      }
      __syncthreads();
      if (w > sb) {
        float xp[16];
        #pragma unroll
        for (int t = 0; t < 16; ++t) xp[t] = Vf[sb * 16 + t][l];
        #pragma unroll
        for (int i = 0; i < 16; ++i) {
          float s2 = cur[i];
          #pragma unroll
          for (int t = 0; t < 16; ++t) s2 -= Lm[w * 16 + i][sb * 16 + t] * xp[t];
          cur[i] = s2;
        }
      }
    }
  }
  {
    int t = tid >> 2, off = (tid & 3) * 16;
    ushort tmp[16];
    #pragma unroll
    for (int i = 0; i < 16; ++i) { tmp[i] = f2b(Vf[t][off + i]); Tb[t * LS + off + i] = tmp[i]; }
    *(uint4*)&TBh[t * 64 + off] = *(const uint4*)&tmp[0];
    *(uint4*)&TBh[t * 64 + off + 8] = *(const uint4*)&tmp[8];
  }
  __syncthreads();
  f32x4 y[4] = {};
  #pragma unroll
  for (int s = 0; s < 2; ++s) {
    bf16x8 af = *(const bf16x8*)&Tb[(w * 16 + lane15) * LS + s * 32 + quad * 8];
    #pragma unroll
    for (int f = 0; f < 4; ++f) {
      bf16x8 bf = *(const bf16x8*)&WT[(f * 16 + lane15) * LS + s * 32 + quad * 8];
      y[f] = MFMA16(af, bf, y[f]);
    }
  }
  #pragma unroll
  for (int f = 0; f < 4; ++f)
    #pragma unroll
    for (int r = 0; r < 4; ++r)
      YBh[(long)(w * 16 + quad * 4 + r) * 64 + f * 16 + lane15] = f2b(y[f][r]);
}

// ---------------- solveB: chunk recurrence; writes X and KZ = K - prefix ----------------
__global__ __launch_bounds__(256) void solveB_kernel(
    const ushort* __restrict__ whb, const ushort* __restrict__ kb,
    const ushort* __restrict__ TB, const ushort* __restrict__ YB,
    ushort* __restrict__ Xb, ushort* __restrict__ KZ)
{
  int h = blockIdx.x;
  int ty = blockIdx.y;
  int js = (ty < 8) ? ty : (23 - ty);
  int j0 = js * 64;
  const ushort* wh_h = whb + (long)h * TTD * HDIM;
  const ushort* k_h = kb + (long)(h >> 1) * 64;
  ushort* X_h = Xb + (long)h * TTD * TTD;
  ushort* KZ_h = KZ + (long)h * 15 * TTD * HDIM;

  __shared__ ushort WT[64 * LS];
  __shared__ ushort XM[64 * LS];
  __shared__ ushort nS[64 * LS];

  int tid = threadIdx.x, w = tid >> 6, l = tid & 63;
  int quad = l >> 4, lane15 = l & 15;
  f32x4 Sacc[4] = {}, Wacc[4] = {};

  float kreg[4][4];
  #pragma unroll
  for (int f = 0; f < 4; ++f)
    #pragma unroll
    for (int r = 0; r < 4; ++r)
      kreg[f][r] = b2f(k_h[(long)(j0 + w * 16 + quad * 4 + r) * DDM + f * 16 + lane15]);

  for (int c = js; c < 16; ++c) {
    const ushort* whc = wh_h + (long)c * 64 * HDIM;
    __syncthreads();
    {
      int d0 = (tid & 7) * 8;
      #pragma unroll
      for (int it = 0; it < 2; ++it) {
        int t = it * 32 + (tid >> 3);
        uint4 pk = *(const uint4*)&whc[(long)t * HDIM + d0];
        const ushort* pu = (const ushort*)&pk;
        #pragma unroll
        for (int i = 0; i < 8; ++i) WT[(d0 + i) * LS + t] = pu[i];
      }
    }
    f32x4 xacc[4] = {};
    if (c == js) {
      f32x4 m[4] = {};
      #pragma unroll
      for (int s = 0; s < 2; ++s) {
        bf16x8 af = *(const bf16x8*)&whc[(long)(w * 16 + lane15) * HDIM + s * 32 + quad * 8];
        #pragma unroll
        for (int f = 0; f < 4; ++f) {
          bf16x8 bk = *(const bf16x8*)&k_h[(long)(j0 + f * 16 + lane15) * DDM + s * 32 + quad * 8];
          m[f] = MFMA16(af, bk, m[f]);
        }
      }
      #pragma unroll
      for (int f = 0; f < 4; ++f)
        #pragma unroll
        for (int r = 0; r < 4; ++r) {
          int t = w * 16 + quad * 4 + r, j = f * 16 + lane15;
          XM[j * LS + t] = (t > j) ? f2b(m[f][r]) : (ushort)0;
        }
      __syncthreads();
      const ushort* TBh = TB + ((long)h * 16 + c) * 4096;
      #pragma unroll
      for (int s = 0; s < 2; ++s) {
        bf16x8 af = *(const bf16x8*)&TBh[(long)(w * 16 + lane15) * 64 + s * 32 + quad * 8];
        #pragma unroll
        for (int f = 0; f < 4; ++f) {
          bf16x8 bf = *(const bf16x8*)&XM[(f * 16 + lane15) * LS + s * 32 + quad * 8];
          xacc[f] = MFMA16(af, bf, xacc[f]);
        }
      }
      __syncthreads();
    } else {
      const ushort* YBh = YB + ((long)h * 16 + c) * 4096;
      #pragma unroll
      for (int s = 0; s < 2; ++s) {
        bf16x8 af = *(const bf16x8*)&YBh[(long)(w * 16 + lane15) * 64 + s * 32 + quad * 8];
        #pragma unroll
        for (int f = 0; f < 4; ++f) {
          bf16x8 bk = *(const bf16x8*)&k_h[(long)(j0 + f * 16 + lane15) * DDM + s * 32 + quad * 8];
          xacc[f] = MFMA16(af, bk, xacc[f]);
          bf16x8 bs = *(const bf16x8*)&nS[(f * 16 + lane15) * LS + s * 32 + quad * 8];
          xacc[f] = MFMA16(af, bs, xacc[f]);
        }
      }
    }
    #pragma unroll
    for (int f = 0; f < 4; ++f)
      #pragma unroll
      for (int r = 0; r < 4; ++r)
        XM[(f * 16 + lane15) * LS + w * 16 + quad * 4 + r] = f2b(xacc[f][r]);
    __syncthreads();
    {
      int j = tid >> 2, seg = (tid & 3) * 16;
      uint2 a0 = *(const uint2*)&XM[j * LS + seg];
      uint2 a1 = *(const uint2*)&XM[j * LS + seg + 4];
      uint2 a2 = *(const uint2*)&XM[j * LS + seg + 8];
      uint2 a3 = *(const uint2*)&XM[j * LS + seg + 12];
      uint4 s0 = {a0.x, a0.y, a1.x, a1.y};
      uint4 s1 = {a2.x, a2.y, a3.x, a3.y};
      *(uint4*)&X_h[(long)(j0 + j) * TTD + c * 64 + seg] = s0;
      *(uint4*)&X_h[(long)(j0 + j) * TTD + c * 64 + seg + 8] = s1;
    }
    if (c < 15) {
      #pragma unroll
      for (int s = 0; s < 2; ++s) {
        bf16x8 aw = *(const bf16x8*)&WT[(w * 16 + lane15) * LS + s * 32 + quad * 8];
        bf16x8 ax = *(const bf16x8*)&XM[(w * 16 + lane15) * LS + s * 32 + quad * 8];
        #pragma unroll
        for (int f = 0; f < 4; ++f) {
          bf16x8 bx = *(const bf16x8*)&XM[(f * 16 + lane15) * LS + s * 32 + quad * 8];
          Sacc[f] = MFMA16(aw, bx, Sacc[f]);
          bf16x8 bw2 = *(const bf16x8*)&WT[(f * 16 + lane15) * LS + s * 32 + quad * 8];
          Wacc[f] = MFMA16(ax, bw2, Wacc[f]);
        }
      }
      ushort* pz = KZ_h + (long)c * TTD * HDIM;
      #pragma unroll
      for (int f = 0; f < 4; ++f)
        #pragma unroll
        for (int r = 0; r < 4; ++r)
          pz[(long)(j0 + w * 16 + quad * 4 + r) * 64 + f * 16 + lane15] =
              f2b(kreg[f][r] - Wacc[f][r]);
      #pragma unroll
      for (int f = 0; f < 4; ++f)
        #pragma unroll
        for (int r = 0; r < 4; ++r)
          nS[(f * 16 + lane15) * LS + w * 16 + quad * 4 + r] = f2b(-Sacc[f][r]);
    }
  }
}

// ---------------- flash: one row tile/block, 2 blocks/CU, async dbuf {KZ,X,V} ----------------
__global__ __launch_bounds__(256) void flash_kernel(
    const ushort* __restrict__ qb, const ushort* __restrict__ kbuf,
    const ushort* __restrict__ whb, const ushort* __restrict__ Xb,
    const ushort* __restrict__ KZ, const ushort* __restrict__ vTb,
    ushort* __restrict__ oall)
{
  int h = blockIdx.x;
  int y = blockIdx.y;
  int ri = (y < 8) ? y : (23 - y);
  int r0 = ri * 64;
  const ushort* q_h = qb + (long)(h >> 1) * 64;
  const ushort* k_h = kbuf + (long)(h >> 1) * 64;
  const ushort* wh_h = whb + (long)h * TTD * HDIM;
  const ushort* X_h = Xb + (long)h * TTD * TTD;
  const ushort* kz = KZ + ((long)h * 15 + (ri - 1)) * TTD * HDIM;
  const ushort* v_h = vTb + (long)(h >> 1) * 64 * TTD;

  __shared__ ushort S[2][3][4096];
  __shared__ ushort KD[4096];
  __shared__ ushort QWD[4096];
  __shared__ ushort PT[4096];

  int tid = threadIdx.x, w = tid >> 6, l = tid & 63;
  int quad = l >> 4, lane15 = l & 15;

  bf16x8 aq[2];
  #pragma unroll
  for (int s = 0; s < 2; ++s)
    aq[s] = *(const bf16x8*)&q_h[(long)(r0 + w * 16 + lane15) * DDM + s * 32 + quad * 8];
  {
    f32x4 t4[4] = {};
    #pragma unroll
    for (int s = 0; s < 2; ++s)
      #pragma unroll
      for (int f = 0; f < 4; ++f) {
        bf16x8 bf = *(const bf16x8*)&wh_h[(long)(r0 + f * 16 + lane15) * HDIM + s * 32 + quad * 8];
        t4[f] = MFMA16(aq[s], bf, t4[f]);
      }
    #pragma unroll
    for (int f = 0; f < 4; ++f)
      #pragma unroll
      for (int r = 0; r < 4; ++r) {
        int i = w * 16 + quad * 4 + r, t = f * 16 + lane15;
        QWD[SWZ(i, f * 2 + (lane15 >> 3)) + (lane15 & 7)] =
            (i >= t) ? f2b(-t4[f][r]) : (ushort)0;
      }
  }
  stage_tile(k_h + (long)r0 * DDM, DDM, KD, w, l);
  if (ri > 0) stage_tile(kz, 64, &S[0][0][0], w, l);
  stage_tile(X_h + r0, TTD, &S[0][1][0], w, l);
  stage_tile(v_h, TTD, &S[0][2][0], w, l);
  __syncthreads();

  f32x4 O[4] = {};
  float m[4], lsum[4];
  #pragma unroll
  for (int r = 0; r < 4; ++r) { m[r] = -1e30f; lsum[r] = 0.f; }

  int cur = 0;
  for (int jb = 0; jb <= ri; ++jb) {
    if (jb < ri) {
      long c0n = (long)(jb + 1) * 64;
      ushort* nb = &S[cur ^ 1][0][0];
      if (jb + 1 < ri) stage_tile(kz + c0n * 64, 64, nb, w, l);
      stage_tile(X_h + c0n * TTD + r0, TTD, nb + 4096, w, l);
      stage_tile(v_h + c0n, TTD, nb + 8192, w, l);
    }
    const ushort* Skz = &S[cur][0][0];
    const ushort* Sx  = &S[cur][1][0];
    const ushort* Sv  = &S[cur][2][0];
    f32x4 acc[4] = {};
    const ushort* Sb = (jb < ri) ? Skz : KD;
    #pragma unroll
    for (int s = 0; s < 2; ++s)
      #pragma unroll
      for (int f = 0; f < 4; ++f)
        acc[f] = MFMA16(aq[s], frag(Sb, f * 16 + lane15, s * 4 + quad), acc[f]);
    #pragma unroll
    for (int s = 0; s < 2; ++s) {
      bf16x8 aw = frag(QWD, w * 16 + lane15, s * 4 + quad);
      #pragma unroll
      for (int f = 0; f < 4; ++f)
        acc[f] = MFMA16(aw, frag(Sx, f * 16 + lane15, s * 4 + quad), acc[f]);
    }
    float rmax[4] = {-3e38f, -3e38f, -3e38f, -3e38f};
    #pragma unroll
    for (int f = 0; f < 4; ++f)
      #pragma unroll
      for (int r = 0; r < 4; ++r) {
        float lv = acc[f][r] * PSCALE;
        if (jb == ri && (f * 16 + lane15) > (w * 16 + quad * 4 + r)) lv = -3e38f;
        acc[f][r] = lv;
        rmax[r] = fmaxf(rmax[r], lv);
      }
    #pragma unroll
    for (int r = 0; r < 4; ++r) {
      rmax[r] = fmaxf(rmax[r], __shfl_xor(rmax[r], 1, 64));
      rmax[r] = fmaxf(rmax[r], __shfl_xor(rmax[r], 2, 64));
      rmax[r] = fmaxf(rmax[r], __shfl_xor(rmax[r], 4, 64));
      rmax[r] = fmaxf(rmax[r], __shfl_xor(rmax[r], 8, 64));
    }
    float alpha[4], rs[4] = {0.f, 0.f, 0.f, 0.f};
    #pragma unroll
    for (int r = 0; r < 4; ++r) {
      float nm = fmaxf(m[r], rmax[r]);
      alpha[r] = __expf(m[r] - nm);
      m[r] = nm;
    }
    #pragma unroll
    for (int f = 0; f < 4; ++f)
      #pragma unroll
      for (int r = 0; r < 4; ++r) {
        float e = __expf(acc[f][r] - m[r]);
        acc[f][r] = e;
        rs[r] += e;
      }
    #pragma unroll
    for (int r = 0; r < 4; ++r) {
      rs[r] += __shfl_xor(rs[r], 1, 64);
      rs[r] += __shfl_xor(rs[r], 2, 64);
      rs[r] += __shfl_xor(rs[r], 4, 64);
      rs[r] += __shfl_xor(rs[r], 8, 64);
      lsum[r] = lsum[r] * alpha[r] + rs[r];
    }
    #pragma unroll
    for (int f = 0; f < 4; ++f)
      #pragma unroll
      for (int r = 0; r < 4; ++r) O[f][r] *= alpha[r];
    #pragma unroll
    for (int f = 0; f < 4; ++f)
      #pragma unroll
      for (int r = 0; r < 4; ++r) {
        int i = w * 16 + quad * 4 + r;
        PT[SWZ(i, f * 2 + (lane15 >> 3)) + (lane15 & 7)] = f2b(acc[f][r]);
      }
    __syncthreads();
    #pragma unroll
    for (int s = 0; s < 2; ++s) {
      bf16x8 ap = frag(PT, w * 16 + lane15, s * 4 + quad);
      #pragma unroll
      for (int f = 0; f < 4; ++f)
        O[f] = MFMA16(ap, frag(Sv, f * 16 + lane15, s * 4 + quad), O[f]);
    }
    __syncthreads();
    cur ^= 1;
  }
  #pragma unroll
  for (int r = 0; r < 4; ++r) lsum[r] = 1.f / lsum[r];
  #pragma unroll
  for (int f = 0; f < 4; ++f)
    #pragma unroll
    for (int r = 0; r < 4; ++r)
      oall[(long)(r0 + w * 16 + quad * 4 + r) * 2048 + h * 64 + f * 16 + lane15] =
          f2b(O[f][r] * lsum[r]);
}

// ---------------- conv(K=3)+SiLU+rotate+normalize -> wh bf16 ----------------
__global__ __launch_bounds__(256) void convdir_kernel(
    const float* __restrict__ w_raw, const float* __restrict__ conv_w,
    const float* __restrict__ omega, const float* __restrict__ phi,
    ushort* __restrict__ whb)
{
  int gid = blockIdx.x * 256 + threadIdx.x;
  int lane = gid & 63;
  int w = gid >> 6;
  int hr = w & 31, t = w >> 5;
  int hkv = hr >> 1, r = hr & 1;
  int cA = hkv * 256 + r * 128 + lane;
  int cB = cA + 64;
  float a = 0.f, b = 0.f;
  #pragma unroll
  for (int i = 0; i < 3; ++i) {
    int tp = t - 2 + i;
    if (tp >= 0) {
      a += w_raw[(long)tp * NOUTW + cA] * conv_w[cA * 3 + i];
      b += w_raw[(long)tp * NOUTW + cB] * conv_w[cB * 3 + i];
    }
  }
  a = a / (1.f + expf(-a));
  b = b / (1.f + expf(-b));
  float th = omega[r] * (float)t + phi[r];
  float wd = a * cosf(th) + b * sinf(th);
  float ss = wd * wd;
  #pragma unroll
  for (int o = 32; o > 0; o >>= 1) ss += __shfl_xor(ss, o, 64);
  float inv = 1.f / sqrtf(ss + 1e-6f);
  whb[((long)hr * TTD + t) * HDIM + lane] = f2b(wd * inv);
}

// ---------------- final GEMM: out = o_all(bf16) @ ow_b^T (async dbuf swizzled) ----------------
__global__ __launch_bounds__(256) void gemm_out_kernel(
    const ushort* __restrict__ A, const ushort* __restrict__ Bb, float* __restrict__ C)
{
  __shared__ ushort Ab[2][4096];
  __shared__ ushort Bt[2][4096];
  int tid = threadIdx.x, w = tid >> 6, l = tid & 63;
  int quad = l >> 4, lane15 = l & 15;
  int rm = blockIdx.y * 64, cn = blockIdx.x * 64;
  const ushort* Ag = A + (long)rm * 2048;
  const ushort* Bg = Bb + (long)cn * 2048;

  stage_tile(Ag, 2048, &Ab[0][0], w, l);
  stage_tile(Bg, 2048, &Bt[0][0], w, l);
  __syncthreads();

  f32x4 acc[4] = {};
  int cur = 0;
  for (int kt = 0; kt < 32; ++kt) {
    if (kt < 31) {
      stage_tile(Ag + (kt + 1) * 64, 2048, &Ab[cur ^ 1][0], w, l);
      stage_tile(Bg + (kt + 1) * 64, 2048, &Bt[cur ^ 1][0], w, l);
    }
    #pragma unroll
    for (int s = 0; s < 2; ++s) {
      bf16x8 af = frag(&Ab[cur][0], w * 16 + lane15, s * 4 + quad);
      #pragma unroll
      for (int f = 0; f < 4; ++f)
        acc[f] = MFMA16(af, frag(&Bt[cur][0], f * 16 + lane15, s * 4 + quad), acc[f]);
    }
    __syncthreads();
    cur ^= 1;
  }
  int orow = rm + w * 16 + quad * 4;
  #pragma unroll
  for (int f = 0; f < 4; ++f)
    #pragma unroll
    for (int r = 0; r < 4; ++r)
      C[(long)(orow + r) * DDM + cn + f * 16 + lane15] = acc[f][r];
}

// ---------------- host ----------------
extern "C" void kernel_launch(void* const* d_in, const int* in_sizes, int n_in,
                              void* d_out, int out_size, void* d_ws, size_t ws_size,
                              hipStream_t stream) {
  const float* hs     = (const float*)d_in[0];
  const float* q_w    = (const float*)d_in[1];
  const float* k_w    = (const float*)d_in[2];
  const float* v_w    = (const float*)d_in[3];
  const float* w1     = (const float*)d_in[4];
  const float* w2     = (const float*)d_in[5];
  const float* conv_w = (const float*)d_in[6];
  const float* bt_w   = (const float*)d_in[7];
  const float* bt_b   = (const float*)d_in[8];
  const float* o_w    = (const float*)d_in[9];
  const float* omega  = (const float*)d_in[10];
  const float* phi    = (const float*)d_in[11];
  float* out = (float*)d_out;
  char* ws = (char*)d_ws;

  ushort* Xb     = (ushort*)(ws + OFF_X);
  ushort* KZb    = (ushort*)(ws + OFF_PZ);
  ushort* hs_b   = (ushort*)(ws + OFF_HSB);
  ushort* qw_wb  = (ushort*)(ws + OFF_QWW);
  ushort* kw_wb  = (ushort*)(ws + OFF_KWW);
  ushort* vw_wb  = (ushort*)(ws + OFF_VWW);
  ushort* w2_b   = (ushort*)(ws + OFF_W2B);
  ushort* wlow_b = (ushort*)(ws + OFF_WLOWB);
  float*  w_raw  = (float*)(ws + OFF_WRAW);
  ushort* TB     = (ushort*)(ws + OFF_TB);
  ushort* o_all  = (ushort*)(ws + OFF_OALL);   // overlays TB after solveB
  ushort* YB     = (ushort*)(ws + OFF_YB);
  ushort* ow_b   = (ushort*)(ws + OFF_OWB);    // overlays YB after solveB
  ushort* wh_b   = (ushort*)(ws + OFF_WHB);
  ushort* q_b    = (ushort*)(ws + OFF_QB);
  ushort* k_b    = (ushort*)(ws + OFF_KB);
  ushort* vT_b   = (ushort*)(ws + OFF_VTB);
  float*  beta   = (float*)(ws + OFF_BETA);
  ushort* bw_b   = (ushort*)(ws + OFF_BW64);

  CvtSegs sg;
  sg.src[0] = hs;   sg.dst[0] = hs_b;          sg.cnt[0] = 1048576;
  sg.src[1] = q_w;  sg.dst[1] = qw_wb;         sg.cnt[1] = 1048576;
  sg.src[2] = k_w;  sg.dst[2] = kw_wb;         sg.cnt[2] = 1048576;
  sg.src[3] = v_w;  sg.dst[3] = vw_wb;         sg.cnt[3] = 1048576;
  sg.src[4] = w2;   sg.dst[4] = w2_b;          sg.cnt[4] = 131072;
  sg.src[5] = bt_w; sg.dst[5] = bw_b;          sg.cnt[5] = 32768;
  sg.src[6] = w1;   sg.dst[6] = bw_b + 32768;  sg.cnt[6] = 32768;
  cvt_all_kernel<<<dim3(4288), 256, 0, stream>>>(sg);

  smallproj_kernel<<<dim3(16), 256, 0, stream>>>(hs_b, bw_b, bt_b, beta, wlow_b);
  qkv_kernel<<<dim3(16, 16, 3), 256, 0, stream>>>(hs_b, qw_wb, kw_wb, vw_wb, q_b, k_b, vT_b);
  wraw_kernel<<<dim3(64, 16), 256, 0, stream>>>(wlow_b, w2_b, w_raw);
  convdir_kernel<<<dim3(8192), 256, 0, stream>>>(w_raw, conv_w, omega, phi, wh_b);

  solveA_kernel<<<dim3(16, 32), 256, 0, stream>>>(wh_b, beta, TB, YB);
  solveB_kernel<<<dim3(32, 16), 256, 0, stream>>>(wh_b, k_b, TB, YB, Xb, KZb);

  // o_w -> bf16 into YB region (dead after solveB)
  cvt_kernel<<<dim3(2048), 256, 0, stream>>>(o_w, ow_b, 2097152L);

  flash_kernel<<<dim3(32, 16), 256, 0, stream>>>(q_b, k_b, wh_b, Xb, KZb, vT_b, o_all);

  gemm_out_kernel<<<dim3(16, 16), 256, 0, stream>>>(o_all, ow_b, out);

  (void)in_sizes; (void)n_in; (void)out_size; (void)ws_size;
}

// Round 10
// 268.433 us; speedup vs baseline: 1.0267x; 1.0267x over previous
//
#include <hip/hip_runtime.h>
#include <math.h>

// ---------------- problem constants ----------------
#define TTD 1024
#define DDM 1024
#define HDIM 64
#define NOUTW 4096
#define PSCALE 0.125f
#define LS 72   // padded LDS stride (solveA only)

typedef __attribute__((ext_vector_type(8))) __bf16 bf16x8;
typedef __attribute__((ext_vector_type(4))) float f32x4;
#define MFMA16(a,b,c) __builtin_amdgcn_mfma_f32_16x16x32_bf16(a,b,c,0,0,0)

__device__ __forceinline__ ushort f2b(float f) {
  unsigned u = __builtin_bit_cast(unsigned, f);
  return (ushort)((u + 0x7fffu + ((u >> 16) & 1u)) >> 16);
}
__device__ __forceinline__ float b2f(ushort u) {
  unsigned v = (unsigned)u << 16;
  return __builtin_bit_cast(float, v);
}

__device__ __forceinline__ void gload_lds16(const ushort* g, ushort* l) {
  __builtin_amdgcn_global_load_lds(
      (const __attribute__((address_space(1))) unsigned*)g,
      (__attribute__((address_space(3))) unsigned*)l, 16, 0, 0);
}

// XOR-swizzled 64x64 bf16 tile: 16B slot index for (row, chunk)
#define SWZ(row, cc) (((row) * 8 + ((cc) ^ ((row) & 7))) * 8)
// swizzled scalar element address (row, col)
#define SWZE(row, col) (SWZ(row, (col) >> 3) + ((col) & 7))

// async-stage one 64x64 tile (rows at gs-elem stride) into swizzled LDS tile
__device__ __forceinline__ void stage_tile(const ushort* gb, long gs, ushort* tile,
                                           int w, int l) {
  int sub = l >> 3, cc = (l & 7) ^ sub;
  #pragma unroll
  for (int it = 0; it < 2; ++it) {
    int q = w * 2 + it;
    gload_lds16(gb + (long)(q * 8 + sub) * gs + cc * 8, &tile[(q * 64 + l) * 8]);
  }
}

__device__ __forceinline__ bf16x8 frag(const ushort* tile, int row, int cc) {
  return *(const bf16x8*)&tile[SWZ(row, cc)];
}

// ---------------- workspace layout (bytes); total = 149,291,008 (proven) ----------------
#define OFF_X     0L            // X bf16 [32][1024 j][1024 t] : 64 MiB
#define OFF_PZ    67108864L     // KZ bf16 [32][15][1024 j][64 d] : 60 MiB (K - prefix)
// aliases inside PZ (all dead before solveB writes KZ):
#define OFF_HSB   67108864L
#define OFF_QWW   69206016L
#define OFF_KWW   71303168L
#define OFF_VWW   73400320L
#define OFF_W2B   75497472L
#define OFF_WLOWB 75759616L
#define OFF_WRAW  83886080L     // fp32 1024x4096, dead after convdir
#define OFF_TB    130023424L    // Tbeta bf16 (solveA->solveB); dead after solveB
#define OFF_OALL  130023424L    // o_all bf16 overlays TB (flash writes after solveB)
#define OFF_YB    134217728L    // Yb bf16 (solveA->solveB); ow_b overlays after solveB
#define OFF_OWB   134217728L
#define OFF_WHB   138412032L    // wh bf16 (live through flash)
#define OFF_QB    142606336L
#define OFF_KB    144703488L
#define OFF_VTB   146800640L
#define OFF_BETA  148897792L
#define OFF_BW64  149159936L    // 64x1024 bf16 [bt_w ; w1]

// ---------------- fp32 -> bf16 convert (generic) ----------------
__global__ __launch_bounds__(256) void cvt_kernel(const float* __restrict__ x,
                                                  ushort* __restrict__ y, long n) {
  long i = ((long)blockIdx.x * 256 + threadIdx.x) * 4;
  if (i >= n) return;
  float4 f = *(const float4*)(x + i);
  ushort4 o;
  o.x = f2b(f.x); o.y = f2b(f.y); o.z = f2b(f.z); o.w = f2b(f.w);
  *(ushort4*)(y + i) = o;
}

// ---------------- merged fp32 -> bf16 convert (7 segments, one launch) ----------------
struct CvtSegs {
  const float* src[7];
  ushort* dst[7];
  long cnt[7];
};
__global__ __launch_bounds__(256) void cvt_all_kernel(CvtSegs sg) {
  long e = ((long)blockIdx.x * 256 + threadIdx.x) * 4;
  #pragma unroll
  for (int s = 0; s < 7; ++s) {
    if (e < sg.cnt[s]) {
      float4 f = *(const float4*)(sg.src[s] + e);
      ushort4 o;
      o.x = f2b(f.x); o.y = f2b(f.y); o.z = f2b(f.z); o.w = f2b(f.w);
      *(ushort4*)(sg.dst[s] + e) = o;
      return;
    }
    e -= sg.cnt[s];
  }
}

// ---------------- fused QKV projections: async dbuf swizzled, 1 barrier/K64 ----------------
__global__ __launch_bounds__(256) void qkv_kernel(
    const ushort* __restrict__ hsb,
    const ushort* __restrict__ wq, const ushort* __restrict__ wk, const ushort* __restrict__ wv,
    ushort* __restrict__ cq, ushort* __restrict__ ck, ushort* __restrict__ cv)
{
  int z = blockIdx.z;
  const ushort* B = (z == 0) ? wq : (z == 1) ? wk : wv;
  __shared__ ushort Ab[2][4096];
  __shared__ ushort Bb[2][4096];
  int tid = threadIdx.x, w = tid >> 6, l = tid & 63;
  int quad = l >> 4, lane15 = l & 15;
  int rm = blockIdx.y * 64, cn = blockIdx.x * 64;
  const ushort* Ag = hsb + (long)rm * DDM;
  const ushort* Bg = B + (long)cn * DDM;

  stage_tile(Ag, DDM, &Ab[0][0], w, l);
  stage_tile(Bg, DDM, &Bb[0][0], w, l);
  __syncthreads();

  f32x4 acc[4] = {};
  int cur = 0;
  for (int kt = 0; kt < 16; ++kt) {
    if (kt < 15) {
      stage_tile(Ag + (kt + 1) * 64, DDM, &Ab[cur ^ 1][0], w, l);
      stage_tile(Bg + (kt + 1) * 64, DDM, &Bb[cur ^ 1][0], w, l);
    }
    #pragma unroll
    for (int s = 0; s < 2; ++s) {
      bf16x8 af = frag(&Ab[cur][0], w * 16 + lane15, s * 4 + quad);
      #pragma unroll
      for (int f = 0; f < 4; ++f)
        acc[f] = MFMA16(af, frag(&Bb[cur][0], f * 16 + lane15, s * 4 + quad), acc[f]);
    }
    __syncthreads();
    cur ^= 1;
  }
  int orow = rm + w * 16 + quad * 4;
  if (z < 2) {
    ushort* Cb = (z == 0) ? cq : ck;
    #pragma unroll
    for (int f = 0; f < 4; ++f)
      #pragma unroll
      for (int r = 0; r < 4; ++r)
        Cb[(long)(orow + r) * DDM + cn + f * 16 + lane15] = f2b(acc[f][r]);
  } else {
    #pragma unroll
    for (int f = 0; f < 4; ++f) {
      ushort4 o;
      o.x = f2b(acc[f][0]); o.y = f2b(acc[f][1]);
      o.z = f2b(acc[f][2]); o.w = f2b(acc[f][3]);
      *(uint4*)&cv[(long)(cn + f * 16 + lane15) * TTD + orow] = *(const uint4*)&o;
    }
  }
}

// ---------------- w_raw GEMM (K=32): w_raw = w_low @ w2^T, fp32 out ----------------
__global__ __launch_bounds__(256) void wraw_kernel(
    const ushort* __restrict__ A, const ushort* __restrict__ B, float* __restrict__ C)
{
  __shared__ ushort As[64 * 32];
  __shared__ ushort Bs[64 * 32];
  int tid = threadIdx.x, w = tid >> 6, l = tid & 63;
  int quad = l >> 4, lane15 = l & 15;
  int rm = blockIdx.y * 64, cn = blockIdx.x * 64;
  int row = tid >> 2, ch = (tid & 3) * 8;
  f32x4 acc[4] = {};
  gload_lds16(A + (long)(rm + row) * 32 + ch, &As[tid * 8]);
  gload_lds16(B + (long)(cn + row) * 32 + ch, &Bs[tid * 8]);
  __syncthreads();
  bf16x8 af = *(const bf16x8*)&As[(w * 16 + lane15) * 32 + quad * 8];
  #pragma unroll
  for (int f = 0; f < 4; ++f) {
    bf16x8 bf = *(const bf16x8*)&Bs[(f * 16 + lane15) * 32 + quad * 8];
    acc[f] = MFMA16(af, bf, acc[f]);
  }
  int orow = rm + w * 16 + quad * 4;
  #pragma unroll
  for (int f = 0; f < 4; ++f)
    #pragma unroll
    for (int r = 0; r < 4; ++r)
      C[(long)(orow + r) * NOUTW + cn + f * 16 + lane15] = acc[f][r];
}

// ---------------- small projections + fused beta: bt/w1 stacked weights ----------------
__global__ __launch_bounds__(256) void smallproj_kernel(
    const ushort* __restrict__ hsb, const ushort* __restrict__ bw,
    const float* __restrict__ bt_b, float* __restrict__ beta,
    ushort* __restrict__ wlowb)
{
  int rm = blockIdx.x * 64;
  int tid = threadIdx.x, w = tid >> 6, l = tid & 63;
  int quad = l >> 4, lane15 = l & 15;
  f32x4 acc[4] = {};
  for (int k0 = 0; k0 < 1024; k0 += 32) {
    bf16x8 af = *(const bf16x8*)&hsb[(long)(rm + w * 16 + lane15) * 1024 + k0 + quad * 8];
    #pragma unroll
    for (int f = 0; f < 4; ++f) {
      bf16x8 bf = *(const bf16x8*)&bw[(long)(f * 16 + lane15) * 1024 + k0 + quad * 8];
      acc[f] = MFMA16(af, bf, acc[f]);
    }
  }
  int orow = rm + w * 16 + quad * 4;
  #pragma unroll
  for (int f = 0; f < 2; ++f) {
    int hr = f * 16 + lane15;
    float bb = bt_b[hr];
    #pragma unroll
    for (int r = 0; r < 4; ++r)
      beta[(long)hr * TTD + orow + r] = 2.f / (1.f + expf(-(acc[f][r] + bb)));
  }
  #pragma unroll
  for (int f = 2; f < 4; ++f)
    #pragma unroll
    for (int r = 0; r < 4; ++r)
      wlowb[(long)(orow + r) * 32 + (f - 2) * 16 + lane15] = f2b(acc[f][r]);
}

// ---------------- solveA: Tbeta = (I+Lm)^-1 diag(beta), Yb = Tbeta.wh ----------------
__global__ __launch_bounds__(256) void solveA_kernel(
    const ushort* __restrict__ whb, const float* __restrict__ beta,
    ushort* __restrict__ TB, ushort* __restrict__ YB)
{
  int c = blockIdx.x, h = blockIdx.y;
  const ushort* whc = whb + ((long)h * TTD + c * 64) * HDIM;
  const float* bet = beta + (long)h * TTD + c * 64;
  ushort* TBh = TB + ((long)h * 16 + c) * 4096;
  ushort* YBh = YB + ((long)h * 16 + c) * 4096;

  __shared__ float Lm[64][65];
  __shared__ float Vf[64][65];
  __shared__ ushort WT[64 * LS];
  __shared__ ushort Tb[64 * LS];

  int tid = threadIdx.x, w = tid >> 6, l = tid & 63;
  int quad = l >> 4, lane15 = l & 15;

  f32x4 g[4] = {};
  #pragma unroll
  for (int s = 0; s < 2; ++s) {
    bf16x8 af = *(const bf16x8*)&whc[(long)(w * 16 + lane15) * HDIM + s * 32 + quad * 8];
    #pragma unroll
    for (int f = 0; f < 4; ++f) {
      bf16x8 bf = *(const bf16x8*)&whc[(long)(f * 16 + lane15) * HDIM + s * 32 + quad * 8];
      g[f] = MFMA16(af, bf, g[f]);
    }
  }
  #pragma unroll
  for (int r = 0; r < 4; ++r) {
    int t = w * 16 + quad * 4 + r;
    float bv = bet[t];
    #pragma unroll
    for (int f = 0; f < 4; ++f) {
      int tp = f * 16 + lane15;
      Lm[t][tp] = (t > tp) ? bv * g[f][r] : 0.f;
    }
  }
  {
    int d0 = (tid & 7) * 8;
    #pragma unroll
    for (int it = 0; it < 2; ++it) {
      int t = it * 32 + (tid >> 3);
      uint4 pk = *(const uint4*)&whc[(long)t * HDIM + d0];
      const ushort* pu = (const ushort*)&pk;
      #pragma unroll
      for (int i = 0; i < 8; ++i) WT[(d0 + i) * LS + t] = pu[i];
    }
  }
  __syncthreads();

  {
    float cur[16];
    #pragma unroll
    for (int i = 0; i < 16; ++i) cur[i] = (w * 16 + i == l) ? bet[l] : 0.f;
    for (int sb = 0; sb < 4; ++sb) {
      if (w == sb) {
        float xloc[16];
        #pragma unroll
        for (int i = 0; i < 16; ++i) {
          float bv = cur[i];
          #pragma unroll
          for (int j2 = 0; j2 < 16; ++j2)
            if (j2 < i) bv -= Lm[sb * 16 + i][sb * 16 + j2] * xloc[j2];
          xloc[i] = bv;
          Vf[sb * 16 + i][l] = bv;
        }
      }
      __syncthreads();
      if (w > sb) {
        float xp[16];
        #pragma unroll
        for (int t = 0; t < 16; ++t) xp[t] = Vf[sb * 16 + t][l];
        #pragma unroll
        for (int i = 0; i < 16; ++i) {
          float s2 = cur[i];
          #pragma unroll
          for (int t = 0; t < 16; ++t) s2 -= Lm[w * 16 + i][sb * 16 + t] * xp[t];
          cur[i] = s2;
        }
      }
    }
  }
  {
    int t = tid >> 2, off = (tid & 3) * 16;
    ushort tmp[16];
    #pragma unroll
    for (int i = 0; i < 16; ++i) { tmp[i] = f2b(Vf[t][off + i]); Tb[t * LS + off + i] = tmp[i]; }
    *(uint4*)&TBh[t * 64 + off] = *(const uint4*)&tmp[0];
    *(uint4*)&TBh[t * 64 + off + 8] = *(const uint4*)&tmp[8];
  }
  __syncthreads();
  f32x4 y[4] = {};
  #pragma unroll
  for (int s = 0; s < 2; ++s) {
    bf16x8 af = *(const bf16x8*)&Tb[(w * 16 + lane15) * LS + s * 32 + quad * 8];
    #pragma unroll
    for (int f = 0; f < 4; ++f) {
      bf16x8 bf = *(const bf16x8*)&WT[(f * 16 + lane15) * LS + s * 32 + quad * 8];
      y[f] = MFMA16(af, bf, y[f]);
    }
  }
  #pragma unroll
  for (int f = 0; f < 4; ++f)
    #pragma unroll
    for (int r = 0; r < 4; ++r)
      YBh[(long)(w * 16 + quad * 4 + r) * 64 + f * 16 + lane15] = f2b(y[f][r]);
}

// ---------------- solveB: chunk recurrence; all tiles XOR-swizzled; K staged once ----------------
__global__ __launch_bounds__(256) void solveB_kernel(
    const ushort* __restrict__ whb, const ushort* __restrict__ kb,
    const ushort* __restrict__ TB, const ushort* __restrict__ YB,
    ushort* __restrict__ Xb, ushort* __restrict__ KZ)
{
  int h = blockIdx.x;
  int ty = blockIdx.y;
  int js = (ty < 8) ? ty : (23 - ty);
  int j0 = js * 64;
  const ushort* wh_h = whb + (long)h * TTD * HDIM;
  const ushort* k_h = kb + (long)(h >> 1) * 64;
  ushort* X_h = Xb + (long)h * TTD * TTD;
  ushort* KZ_h = KZ + (long)h * 15 * TTD * HDIM;

  __shared__ ushort KT[4096];   // K slab [j][d], staged once
  __shared__ ushort WT[4096];   // wh^T [d][t]
  __shared__ ushort XM[4096];   // X chunk [j][t]
  __shared__ ushort nS[4096];   // -S [j][d]

  int tid = threadIdx.x, w = tid >> 6, l = tid & 63;
  int quad = l >> 4, lane15 = l & 15;
  f32x4 Sacc[4] = {}, Wacc[4] = {};

  // async-stage K slab once (drained at first B0)
  stage_tile(k_h + (long)j0 * DDM, DDM, KT, w, l);

  // K in C-layout registers for the KZ write
  float kreg[4][4];
  #pragma unroll
  for (int f = 0; f < 4; ++f)
    #pragma unroll
    for (int r = 0; r < 4; ++r)
      kreg[f][r] = b2f(k_h[(long)(j0 + w * 16 + quad * 4 + r) * DDM + f * 16 + lane15]);

  for (int c = js; c < 16; ++c) {
    const ushort* whc = wh_h + (long)c * 64 * HDIM;
    __syncthreads();  // B0: prev iter's WT/XM reads done; nS visible; (first iter: KT drained)
    // stage WT[d][t] = transpose of whc (swizzled scalar stores: bank-spread)
    {
      int d0 = (tid & 7) * 8;
      #pragma unroll
      for (int it = 0; it < 2; ++it) {
        int t = it * 32 + (tid >> 3);
        uint4 pk = *(const uint4*)&whc[(long)t * HDIM + d0];
        const ushort* pu = (const ushort*)&pk;
        #pragma unroll
        for (int i = 0; i < 8; ++i) WT[SWZE(d0 + i, t)] = pu[i];
      }
    }
    f32x4 xacc[4] = {};
    if (c == js) {
      // M = wh.K^T (A = wh rows direct global; B = KT frags)
      f32x4 m[4] = {};
      #pragma unroll
      for (int s = 0; s < 2; ++s) {
        bf16x8 af = *(const bf16x8*)&whc[(long)(w * 16 + lane15) * HDIM + s * 32 + quad * 8];
        #pragma unroll
        for (int f = 0; f < 4; ++f)
          m[f] = MFMA16(af, frag(KT, f * 16 + lane15, s * 4 + quad), m[f]);
      }
      #pragma unroll
      for (int f = 0; f < 4; ++f)
        #pragma unroll
        for (int r = 0; r < 4; ++r) {
          int t = w * 16 + quad * 4 + r, j = f * 16 + lane15;
          XM[SWZE(j, t)] = (t > j) ? f2b(m[f][r]) : (ushort)0;
        }
      __syncthreads();  // B1: Mt visible (KT frag reads also done)
      const ushort* TBh = TB + ((long)h * 16 + c) * 4096;
      #pragma unroll
      for (int s = 0; s < 2; ++s) {
        bf16x8 af = *(const bf16x8*)&TBh[(long)(w * 16 + lane15) * 64 + s * 32 + quad * 8];
        #pragma unroll
        for (int f = 0; f < 4; ++f)
          xacc[f] = MFMA16(af, frag(XM, f * 16 + lane15, s * 4 + quad), xacc[f]);
      }
      __syncthreads();  // B1b: Mt reads done before Xl overwrite
    } else {
      // X = Yb.(K^T - S): A = YB global frags; B = KT + nS frags
      const ushort* YBh = YB + ((long)h * 16 + c) * 4096;
      #pragma unroll
      for (int s = 0; s < 2; ++s) {
        bf16x8 af = *(const bf16x8*)&YBh[(long)(w * 16 + lane15) * 64 + s * 32 + quad * 8];
        #pragma unroll
        for (int f = 0; f < 4; ++f) {
          xacc[f] = MFMA16(af, frag(KT, f * 16 + lane15, s * 4 + quad), xacc[f]);
          xacc[f] = MFMA16(af, frag(nS, f * 16 + lane15, s * 4 + quad), xacc[f]);
        }
      }
    }
    // stage Xl[j][t] (swizzled transposed scalar stores)
    #pragma unroll
    for (int f = 0; f < 4; ++f)
      #pragma unroll
      for (int r = 0; r < 4; ++r)
        XM[SWZE(f * 16 + lane15, w * 16 + quad * 4 + r)] = f2b(xacc[f][r]);
    __syncthreads();  // B2: XM + WT visible
    // global X write via b128 frag reads (conflict-free)
    {
      int j = tid >> 2, c2 = (tid & 3) * 2;
      bf16x8 s0 = frag(XM, j, c2);
      bf16x8 s1 = frag(XM, j, c2 + 1);
      *(bf16x8*)&X_h[(long)(j0 + j) * TTD + c * 64 + c2 * 8] = s0;
      *(bf16x8*)&X_h[(long)(j0 + j) * TTD + c * 64 + c2 * 8 + 8] = s1;
    }
    if (c < 15) {
      // S[d][j] += WT @ XM ; W[j][d] += XM @ WT  (all frags)
      #pragma unroll
      for (int s = 0; s < 2; ++s) {
        bf16x8 aw = frag(WT, w * 16 + lane15, s * 4 + quad);
        bf16x8 ax = frag(XM, w * 16 + lane15, s * 4 + quad);
        #pragma unroll
        for (int f = 0; f < 4; ++f) {
          Sacc[f] = MFMA16(aw, frag(XM, f * 16 + lane15, s * 4 + quad), Sacc[f]);
          Wacc[f] = MFMA16(ax, frag(WT, f * 16 + lane15, s * 4 + quad), Wacc[f]);
        }
      }
      // KZ level c = K - prefix
      ushort* pz = KZ_h + (long)c * TTD * HDIM;
      #pragma unroll
      for (int f = 0; f < 4; ++f)
        #pragma unroll
        for (int r = 0; r < 4; ++r)
          pz[(long)(j0 + w * 16 + quad * 4 + r) * 64 + f * 16 + lane15] =
              f2b(kreg[f][r] - Wacc[f][r]);
      // refresh nS[j][d] = -S (swizzled transposed scalar stores)
      #pragma unroll
      for (int f = 0; f < 4; ++f)
        #pragma unroll
        for (int r = 0; r < 4; ++r)
          nS[SWZE(f * 16 + lane15, w * 16 + quad * 4 + r)] = f2b(-Sacc[f][r]);
    }
  }
}

// ---------------- flash: one row tile/block, 2 blocks/CU, async dbuf {KZ,X,V} ----------------
__global__ __launch_bounds__(256) void flash_kernel(
    const ushort* __restrict__ qb, const ushort* __restrict__ kbuf,
    const ushort* __restrict__ whb, const ushort* __restrict__ Xb,
    const ushort* __restrict__ KZ, const ushort* __restrict__ vTb,
    ushort* __restrict__ oall)
{
  int h = blockIdx.x;
  int y = blockIdx.y;
  int ri = (y < 8) ? y : (23 - y);
  int r0 = ri * 64;
  const ushort* q_h = qb + (long)(h >> 1) * 64;
  const ushort* k_h = kbuf + (long)(h >> 1) * 64;
  const ushort* wh_h = whb + (long)h * TTD * HDIM;
  const ushort* X_h = Xb + (long)h * TTD * TTD;
  const ushort* kz = KZ + ((long)h * 15 + (ri - 1)) * TTD * HDIM;
  const ushort* v_h = vTb + (long)(h >> 1) * 64 * TTD;

  __shared__ ushort S[2][3][4096];
  __shared__ ushort KD[4096];
  __shared__ ushort QWD[4096];
  __shared__ ushort PT[4096];

  int tid = threadIdx.x, w = tid >> 6, l = tid & 63;
  int quad = l >> 4, lane15 = l & 15;

  bf16x8 aq[2];
  #pragma unroll
  for (int s = 0; s < 2; ++s)
    aq[s] = *(const bf16x8*)&q_h[(long)(r0 + w * 16 + lane15) * DDM + s * 32 + quad * 8];
  {
    f32x4 t4[4] = {};
    #pragma unroll
    for (int s = 0; s < 2; ++s)
      #pragma unroll
      for (int f = 0; f < 4; ++f) {
        bf16x8 bf = *(const bf16x8*)&wh_h[(long)(r0 + f * 16 + lane15) * HDIM + s * 32 + quad * 8];
        t4[f] = MFMA16(aq[s], bf, t4[f]);
      }
    #pragma unroll
    for (int f = 0; f < 4; ++f)
      #pragma unroll
      for (int r = 0; r < 4; ++r) {
        int i = w * 16 + quad * 4 + r, t = f * 16 + lane15;
        QWD[SWZE(i, t)] = (i >= t) ? f2b(-t4[f][r]) : (ushort)0;
      }
  }
  stage_tile(k_h + (long)r0 * DDM, DDM, KD, w, l);
  if (ri > 0) stage_tile(kz, 64, &S[0][0][0], w, l);
  stage_tile(X_h + r0, TTD, &S[0][1][0], w, l);
  stage_tile(v_h, TTD, &S[0][2][0], w, l);
  __syncthreads();

  f32x4 O[4] = {};
  float m[4], lsum[4];
  #pragma unroll
  for (int r = 0; r < 4; ++r) { m[r] = -1e30f; lsum[r] = 0.f; }

  int cur = 0;
  for (int jb = 0; jb <= ri; ++jb) {
    if (jb < ri) {
      long c0n = (long)(jb + 1) * 64;
      ushort* nb = &S[cur ^ 1][0][0];
      if (jb + 1 < ri) stage_tile(kz + c0n * 64, 64, nb, w, l);
      stage_tile(X_h + c0n * TTD + r0, TTD, nb + 4096, w, l);
      stage_tile(v_h + c0n, TTD, nb + 8192, w, l);
    }
    const ushort* Skz = &S[cur][0][0];
    const ushort* Sx  = &S[cur][1][0];
    const ushort* Sv  = &S[cur][2][0];
    f32x4 acc[4] = {};
    const ushort* Sb = (jb < ri) ? Skz : KD;
    #pragma unroll
    for (int s = 0; s < 2; ++s)
      #pragma unroll
      for (int f = 0; f < 4; ++f)
        acc[f] = MFMA16(aq[s], frag(Sb, f * 16 + lane15, s * 4 + quad), acc[f]);
    #pragma unroll
    for (int s = 0; s < 2; ++s) {
      bf16x8 aw = frag(QWD, w * 16 + lane15, s * 4 + quad);
      #pragma unroll
      for (int f = 0; f < 4; ++f)
        acc[f] = MFMA16(aw, frag(Sx, f * 16 + lane15, s * 4 + quad), acc[f]);
    }
    float rmax[4] = {-3e38f, -3e38f, -3e38f, -3e38f};
    #pragma unroll
    for (int f = 0; f < 4; ++f)
      #pragma unroll
      for (int r = 0; r < 4; ++r) {
        float lv = acc[f][r] * PSCALE;
        if (jb == ri && (f * 16 + lane15) > (w * 16 + quad * 4 + r)) lv = -3e38f;
        acc[f][r] = lv;
        rmax[r] = fmaxf(rmax[r], lv);
      }
    #pragma unroll
    for (int r = 0; r < 4; ++r) {
      rmax[r] = fmaxf(rmax[r], __shfl_xor(rmax[r], 1, 64));
      rmax[r] = fmaxf(rmax[r], __shfl_xor(rmax[r], 2, 64));
      rmax[r] = fmaxf(rmax[r], __shfl_xor(rmax[r], 4, 64));
      rmax[r] = fmaxf(rmax[r], __shfl_xor(rmax[r], 8, 64));
    }
    float alpha[4], rs[4] = {0.f, 0.f, 0.f, 0.f};
    #pragma unroll
    for (int r = 0; r < 4; ++r) {
      float nm = fmaxf(m[r], rmax[r]);
      alpha[r] = __expf(m[r] - nm);
      m[r] = nm;
    }
    #pragma unroll
    for (int f = 0; f < 4; ++f)
      #pragma unroll
      for (int r = 0; r < 4; ++r) {
        float e = __expf(acc[f][r] - m[r]);
        acc[f][r] = e;
        rs[r] += e;
      }
    #pragma unroll
    for (int r = 0; r < 4; ++r) {
      rs[r] += __shfl_xor(rs[r], 1, 64);
      rs[r] += __shfl_xor(rs[r], 2, 64);
      rs[r] += __shfl_xor(rs[r], 4, 64);
      rs[r] += __shfl_xor(rs[r], 8, 64);
      lsum[r] = lsum[r] * alpha[r] + rs[r];
    }
    #pragma unroll
    for (int f = 0; f < 4; ++f)
      #pragma unroll
      for (int r = 0; r < 4; ++r) O[f][r] *= alpha[r];
    #pragma unroll
    for (int f = 0; f < 4; ++f)
      #pragma unroll
      for (int r = 0; r < 4; ++r) {
        int i = w * 16 + quad * 4 + r;
        PT[SWZE(i, f * 16 + lane15)] = f2b(acc[f][r]);
      }
    __syncthreads();
    #pragma unroll
    for (int s = 0; s < 2; ++s) {
      bf16x8 ap = frag(PT, w * 16 + lane15, s * 4 + quad);
      #pragma unroll
      for (int f = 0; f < 4; ++f)
        O[f] = MFMA16(ap, frag(Sv, f * 16 + lane15, s * 4 + quad), O[f]);
    }
    __syncthreads();
    cur ^= 1;
  }
  #pragma unroll
  for (int r = 0; r < 4; ++r) lsum[r] = 1.f / lsum[r];
  #pragma unroll
  for (int f = 0; f < 4; ++f)
    #pragma unroll
    for (int r = 0; r < 4; ++r)
      oall[(long)(r0 + w * 16 + quad * 4 + r) * 2048 + h * 64 + f * 16 + lane15] =
          f2b(O[f][r] * lsum[r]);
}

// ---------------- conv(K=3)+SiLU+rotate+normalize -> wh bf16 ----------------
__global__ __launch_bounds__(256) void convdir_kernel(
    const float* __restrict__ w_raw, const float* __restrict__ conv_w,
    const float* __restrict__ omega, const float* __restrict__ phi,
    ushort* __restrict__ whb)
{
  int gid = blockIdx.x * 256 + threadIdx.x;
  int lane = gid & 63;
  int w = gid >> 6;
  int hr = w & 31, t = w >> 5;
  int hkv = hr >> 1, r = hr & 1;
  int cA = hkv * 256 + r * 128 + lane;
  int cB = cA + 64;
  float a = 0.f, b = 0.f;
  #pragma unroll
  for (int i = 0; i < 3; ++i) {
    int tp = t - 2 + i;
    if (tp >= 0) {
      a += w_raw[(long)tp * NOUTW + cA] * conv_w[cA * 3 + i];
      b += w_raw[(long)tp * NOUTW + cB] * conv_w[cB * 3 + i];
    }
  }
  a = a / (1.f + expf(-a));
  b = b / (1.f + expf(-b));
  float th = omega[r] * (float)t + phi[r];
  float wd = a * cosf(th) + b * sinf(th);
  float ss = wd * wd;
  #pragma unroll
  for (int o = 32; o > 0; o >>= 1) ss += __shfl_xor(ss, o, 64);
  float inv = 1.f / sqrtf(ss + 1e-6f);
  whb[((long)hr * TTD + t) * HDIM + lane] = f2b(wd * inv);
}

// ---------------- final GEMM: out = o_all(bf16) @ ow_b^T (async dbuf swizzled) ----------------
__global__ __launch_bounds__(256) void gemm_out_kernel(
    const ushort* __restrict__ A, const ushort* __restrict__ Bb, float* __restrict__ C)
{
  __shared__ ushort Ab[2][4096];
  __shared__ ushort Bt[2][4096];
  int tid = threadIdx.x, w = tid >> 6, l = tid & 63;
  int quad = l >> 4, lane15 = l & 15;
  int rm = blockIdx.y * 64, cn = blockIdx.x * 64;
  const ushort* Ag = A + (long)rm * 2048;
  const ushort* Bg = Bb + (long)cn * 2048;

  stage_tile(Ag, 2048, &Ab[0][0], w, l);
  stage_tile(Bg, 2048, &Bt[0][0], w, l);
  __syncthreads();

  f32x4 acc[4] = {};
  int cur = 0;
  for (int kt = 0; kt < 32; ++kt) {
    if (kt < 31) {
      stage_tile(Ag + (kt + 1) * 64, 2048, &Ab[cur ^ 1][0], w, l);
      stage_tile(Bg + (kt + 1) * 64, 2048, &Bt[cur ^ 1][0], w, l);
    }
    #pragma unroll
    for (int s = 0; s < 2; ++s) {
      bf16x8 af = frag(&Ab[cur][0], w * 16 + lane15, s * 4 + quad);
      #pragma unroll
      for (int f = 0; f < 4; ++f)
        acc[f] = MFMA16(af, frag(&Bt[cur][0], f * 16 + lane15, s * 4 + quad), acc[f]);
    }
    __syncthreads();
    cur ^= 1;
  }
  int orow = rm + w * 16 + quad * 4;
  #pragma unroll
  for (int f = 0; f < 4; ++f)
    #pragma unroll
    for (int r = 0; r < 4; ++r)
      C[(long)(orow + r) * DDM + cn + f * 16 + lane15] = acc[f][r];
}

// ---------------- host ----------------
extern "C" void kernel_launch(void* const* d_in, const int* in_sizes, int n_in,
                              void* d_out, int out_size, void* d_ws, size_t ws_size,
                              hipStream_t stream) {
  const float* hs     = (const float*)d_in[0];
  const float* q_w    = (const float*)d_in[1];
  const float* k_w    = (const float*)d_in[2];
  const float* v_w    = (const float*)d_in[3];
  const float* w1     = (const float*)d_in[4];
  const float* w2     = (const float*)d_in[5];
  const float* conv_w = (const float*)d_in[6];
  const float* bt_w   = (const float*)d_in[7];
  const float* bt_b   = (const float*)d_in[8];
  const float* o_w    = (const float*)d_in[9];
  const float* omega  = (const float*)d_in[10];
  const float* phi    = (const float*)d_in[11];
  float* out = (float*)d_out;
  char* ws = (char*)d_ws;

  ushort* Xb     = (ushort*)(ws + OFF_X);
  ushort* KZb    = (ushort*)(ws + OFF_PZ);
  ushort* hs_b   = (ushort*)(ws + OFF_HSB);
  ushort* qw_wb  = (ushort*)(ws + OFF_QWW);
  ushort* kw_wb  = (ushort*)(ws + OFF_KWW);
  ushort* vw_wb  = (ushort*)(ws + OFF_VWW);
  ushort* w2_b   = (ushort*)(ws + OFF_W2B);
  ushort* wlow_b = (ushort*)(ws + OFF_WLOWB);
  float*  w_raw  = (float*)(ws + OFF_WRAW);
  ushort* TB     = (ushort*)(ws + OFF_TB);
  ushort* o_all  = (ushort*)(ws + OFF_OALL);   // overlays TB after solveB
  ushort* YB     = (ushort*)(ws + OFF_YB);
  ushort* ow_b   = (ushort*)(ws + OFF_OWB);    // overlays YB after solveB
  ushort* wh_b   = (ushort*)(ws + OFF_WHB);
  ushort* q_b    = (ushort*)(ws + OFF_QB);
  ushort* k_b    = (ushort*)(ws + OFF_KB);
  ushort* vT_b   = (ushort*)(ws + OFF_VTB);
  float*  beta   = (float*)(ws + OFF_BETA);
  ushort* bw_b   = (ushort*)(ws + OFF_BW64);

  CvtSegs sg;
  sg.src[0] = hs;   sg.dst[0] = hs_b;          sg.cnt[0] = 1048576;
  sg.src[1] = q_w;  sg.dst[1] = qw_wb;         sg.cnt[1] = 1048576;
  sg.src[2] = k_w;  sg.dst[2] = kw_wb;         sg.cnt[2] = 1048576;
  sg.src[3] = v_w;  sg.dst[3] = vw_wb;         sg.cnt[3] = 1048576;
  sg.src[4] = w2;   sg.dst[4] = w2_b;          sg.cnt[4] = 131072;
  sg.src[5] = bt_w; sg.dst[5] = bw_b;          sg.cnt[5] = 32768;
  sg.src[6] = w1;   sg.dst[6] = bw_b + 32768;  sg.cnt[6] = 32768;
  cvt_all_kernel<<<dim3(4288), 256, 0, stream>>>(sg);

  smallproj_kernel<<<dim3(16), 256, 0, stream>>>(hs_b, bw_b, bt_b, beta, wlow_b);
  qkv_kernel<<<dim3(16, 16, 3), 256, 0, stream>>>(hs_b, qw_wb, kw_wb, vw_wb, q_b, k_b, vT_b);
  wraw_kernel<<<dim3(64, 16), 256, 0, stream>>>(wlow_b, w2_b, w_raw);
  convdir_kernel<<<dim3(8192), 256, 0, stream>>>(w_raw, conv_w, omega, phi, wh_b);

  solveA_kernel<<<dim3(16, 32), 256, 0, stream>>>(wh_b, beta, TB, YB);
  solveB_kernel<<<dim3(32, 16), 256, 0, stream>>>(wh_b, k_b, TB, YB, Xb, KZb);

  // o_w -> bf16 into YB region (dead after solveB)
  cvt_kernel<<<dim3(2048), 256, 0, stream>>>(o_w, ow_b, 2097152L);

  flash_kernel<<<dim3(32, 16), 256, 0, stream>>>(q_b, k_b, wh_b, Xb, KZb, vT_b, o_all);

  gemm_out_kernel<<<dim3(16, 16), 256, 0, stream>>>(o_all, ow_b, out);

  (void)in_sizes; (void)n_in; (void)out_size; (void)ws_size;
}

// Round 12
// 258.463 us; speedup vs baseline: 1.0663x; 1.0386x over previous
//
#include <hip/hip_runtime.h>
#include <math.h>

// ---------------- problem constants ----------------
#define TTD 1024
#define DDM 1024
#define HDIM 64
#define NOUTW 4096
#define PSCALE 0.125f
#define LS 72   // padded LDS stride (solveA only)

typedef __attribute__((ext_vector_type(8))) __bf16 bf16x8;
typedef __attribute__((ext_vector_type(4))) float f32x4;
#define MFMA16(a,b,c) __builtin_amdgcn_mfma_f32_16x16x32_bf16(a,b,c,0,0,0)

__device__ __forceinline__ ushort f2b(float f) {
  unsigned u = __builtin_bit_cast(unsigned, f);
  return (ushort)((u + 0x7fffu + ((u >> 16) & 1u)) >> 16);
}
__device__ __forceinline__ float b2f(ushort u) {
  unsigned v = (unsigned)u << 16;
  return __builtin_bit_cast(float, v);
}

__device__ __forceinline__ void gload_lds16(const ushort* g, ushort* l) {
  __builtin_amdgcn_global_load_lds(
      (const __attribute__((address_space(1))) unsigned*)g,
      (__attribute__((address_space(3))) unsigned*)l, 16, 0, 0);
}

// XOR-swizzled 64x64 bf16 tile: 16B slot index for (row, chunk)
#define SWZ(row, cc) (((row) * 8 + ((cc) ^ ((row) & 7))) * 8)
// swizzled scalar element address (row, col)
#define SWZE(row, col) (SWZ(row, (col) >> 3) + ((col) & 7))

// async-stage one 64x64 tile (rows at gs-elem stride) into swizzled LDS tile
__device__ __forceinline__ void stage_tile(const ushort* gb, long gs, ushort* tile,
                                           int w, int l) {
  int sub = l >> 3, cc = (l & 7) ^ sub;
  #pragma unroll
  for (int it = 0; it < 2; ++it) {
    int q = w * 2 + it;
    gload_lds16(gb + (long)(q * 8 + sub) * gs + cc * 8, &tile[(q * 64 + l) * 8]);
  }
}

__device__ __forceinline__ bf16x8 frag(const ushort* tile, int row, int cc) {
  return *(const bf16x8*)&tile[SWZ(row, cc)];
}

// ---------------- workspace layout (bytes); total = 149,291,008 (proven) ----------------
#define OFF_X     0L            // X bf16 [32][1024 j][1024 t] : 64 MiB
#define OFF_PZ    67108864L     // KZ bf16 [32][15][1024 j][64 d] : 60 MiB (K - prefix)
// aliases inside PZ (all dead before solveB writes KZ):
#define OFF_HSB   67108864L
#define OFF_QWW   69206016L
#define OFF_KWW   71303168L
#define OFF_VWW   73400320L
#define OFF_W2B   75497472L
#define OFF_WLOWB 75759616L
#define OFF_TB    130023424L    // Tbeta bf16 (solveA->solveB); dead after solveB
#define OFF_OALL  130023424L    // o_all bf16 overlays TB (flash writes after solveB)
#define OFF_YB    134217728L    // Yb bf16 (solveA->solveB); ow_b overlays after solveB
#define OFF_OWB   134217728L
#define OFF_WHB   138412032L    // wh bf16 (live through flash)
#define OFF_QB    142606336L
#define OFF_KB    144703488L
#define OFF_VTB   146800640L
#define OFF_BETA  148897792L
#define OFF_BW64  149159936L    // 64x1024 bf16 [bt_w ; w1]

// ---------------- fp32 -> bf16 convert (generic) ----------------
__global__ __launch_bounds__(256) void cvt_kernel(const float* __restrict__ x,
                                                  ushort* __restrict__ y, long n) {
  long i = ((long)blockIdx.x * 256 + threadIdx.x) * 4;
  if (i >= n) return;
  float4 f = *(const float4*)(x + i);
  ushort4 o;
  o.x = f2b(f.x); o.y = f2b(f.y); o.z = f2b(f.z); o.w = f2b(f.w);
  *(ushort4*)(y + i) = o;
}

// ---------------- merged fp32 -> bf16 convert (6 segments, one launch) ----------------
// total elems = 4*1048576 + 131072 + 32768 = 4,358,144  -> grid (TOTAL+1023)/1024 = 4256
#define CVT_TOTAL 4358144L
struct CvtSegs {
  const float* src[6];
  ushort* dst[6];
  long cnt[6];
};
__global__ __launch_bounds__(256) void cvt_all_kernel(CvtSegs sg) {
  long e = ((long)blockIdx.x * 256 + threadIdx.x) * 4;
  #pragma unroll
  for (int s = 0; s < 6; ++s) {
    if (e < sg.cnt[s]) {
      float4 f = *(const float4*)(sg.src[s] + e);
      ushort4 o;
      o.x = f2b(f.x); o.y = f2b(f.y); o.z = f2b(f.z); o.w = f2b(f.w);
      *(ushort4*)(sg.dst[s] + e) = o;
      return;
    }
    e -= sg.cnt[s];
  }
}

// ---------------- fused QKV + small projections: z in {Q,K,V, small} ----------------
__global__ __launch_bounds__(256) void qkv_sp_kernel(
    const ushort* __restrict__ hsb,
    const ushort* __restrict__ wq, const ushort* __restrict__ wk, const ushort* __restrict__ wv,
    const ushort* __restrict__ bw, const float* __restrict__ bt_b,
    ushort* __restrict__ cq, ushort* __restrict__ ck, ushort* __restrict__ cv,
    float* __restrict__ beta, ushort* __restrict__ wlowb)
{
  int z = blockIdx.z;
  int tid = threadIdx.x, w = tid >> 6, l = tid & 63;
  int quad = l >> 4, lane15 = l & 15;

  if (z == 3) {
    // smallproj: only x==0 column of blocks does work
    if (blockIdx.x != 0) return;
    int rm = blockIdx.y * 64;
    f32x4 acc[4] = {};
    for (int k0 = 0; k0 < 1024; k0 += 32) {
      bf16x8 af = *(const bf16x8*)&hsb[(long)(rm + w * 16 + lane15) * 1024 + k0 + quad * 8];
      #pragma unroll
      for (int f = 0; f < 4; ++f) {
        bf16x8 bf = *(const bf16x8*)&bw[(long)(f * 16 + lane15) * 1024 + k0 + quad * 8];
        acc[f] = MFMA16(af, bf, acc[f]);
      }
    }
    int orow = rm + w * 16 + quad * 4;
    #pragma unroll
    for (int f = 0; f < 2; ++f) {
      int hr = f * 16 + lane15;
      float bb = bt_b[hr];
      #pragma unroll
      for (int r = 0; r < 4; ++r)
        beta[(long)hr * TTD + orow + r] = 2.f / (1.f + expf(-(acc[f][r] + bb)));
    }
    #pragma unroll
    for (int f = 2; f < 4; ++f)
      #pragma unroll
      for (int r = 0; r < 4; ++r)
        wlowb[(long)(orow + r) * 32 + (f - 2) * 16 + lane15] = f2b(acc[f][r]);
    return;
  }

  const ushort* B = (z == 0) ? wq : (z == 1) ? wk : wv;
  __shared__ ushort Ab[2][4096];
  __shared__ ushort Bb[2][4096];
  int rm = blockIdx.y * 64, cn = blockIdx.x * 64;
  const ushort* Ag = hsb + (long)rm * DDM;
  const ushort* Bg = B + (long)cn * DDM;

  stage_tile(Ag, DDM, &Ab[0][0], w, l);
  stage_tile(Bg, DDM, &Bb[0][0], w, l);
  __syncthreads();

  f32x4 acc[4] = {};
  int cur = 0;
  for (int kt = 0; kt < 16; ++kt) {
    if (kt < 15) {
      stage_tile(Ag + (kt + 1) * 64, DDM, &Ab[cur ^ 1][0], w, l);
      stage_tile(Bg + (kt + 1) * 64, DDM, &Bb[cur ^ 1][0], w, l);
    }
    #pragma unroll
    for (int s = 0; s < 2; ++s) {
      bf16x8 af = frag(&Ab[cur][0], w * 16 + lane15, s * 4 + quad);
      #pragma unroll
      for (int f = 0; f < 4; ++f)
        acc[f] = MFMA16(af, frag(&Bb[cur][0], f * 16 + lane15, s * 4 + quad), acc[f]);
    }
    __syncthreads();
    cur ^= 1;
  }
  int orow = rm + w * 16 + quad * 4;
  if (z < 2) {
    ushort* Cb = (z == 0) ? cq : ck;
    #pragma unroll
    for (int f = 0; f < 4; ++f)
      #pragma unroll
      for (int r = 0; r < 4; ++r)
        Cb[(long)(orow + r) * DDM + cn + f * 16 + lane15] = f2b(acc[f][r]);
  } else {
    #pragma unroll
    for (int f = 0; f < 4; ++f) {
      ushort4 o;
      o.x = f2b(acc[f][0]); o.y = f2b(acc[f][1]);
      o.z = f2b(acc[f][2]); o.w = f2b(acc[f][3]);
      *(uint4*)&cv[(long)(cn + f * 16 + lane15) * TTD + orow] = *(const uint4*)&o;
    }
  }
}

// ---------------- fused w_raw GEMM + conv + SiLU + rotate + normalize -> wh ----------------
__global__ __launch_bounds__(256) void wrawconv_kernel(
    const ushort* __restrict__ wlowb, const ushort* __restrict__ w2b,
    const float* __restrict__ conv_w, const float* __restrict__ omega,
    const float* __restrict__ phi, ushort* __restrict__ whb)
{
  int rm = blockIdx.x * 64;
  int p = blockIdx.y;             // hr
  int hkv = p >> 1, r = p & 1;
  int c0 = hkv * 256 + r * 128;

  __shared__ ushort As[64 * 32];
  __shared__ ushort Bs[128 * 32];
  __shared__ float WR[66][132];   // rows rm-2 .. rm+63 ; cols 0..127

  int tid = threadIdx.x, w = tid >> 6, l = tid & 63;
  int quad = l >> 4, lane15 = l & 15;

  // async-stage A (w_low rows) + B (w2 rows, 128)
  {
    int row = tid >> 2, ch = (tid & 3) * 8;
    gload_lds16(wlowb + (long)(rm + row) * 32 + ch, &As[row * 32 + ch]);
    gload_lds16(w2b + (long)(c0 + row) * 32 + ch, &Bs[row * 32 + ch]);
    gload_lds16(w2b + (long)(c0 + 64 + row) * 32 + ch, &Bs[(64 + row) * 32 + ch]);
  }
  // halo rows rm-2, rm-1 (VALU dot; zero when rm==0 -> causal pad)
  {
    int hr2 = tid >> 7, col = tid & 127;
    float acc = 0.f;
    if (rm > 0) {
      long t = rm - 2 + hr2;
      for (int k = 0; k < 32; ++k)
        acc += b2f(wlowb[t * 32 + k]) * b2f(w2b[(long)(c0 + col) * 32 + k]);
    }
    WR[hr2][col] = acc;
  }
  __syncthreads();

  // main 64x128 GEMM via MFMA (two 64-col halves)
  #pragma unroll
  for (int g = 0; g < 2; ++g) {
    f32x4 acc[4] = {};
    bf16x8 af = *(const bf16x8*)&As[(w * 16 + lane15) * 32 + quad * 8];
    #pragma unroll
    for (int f = 0; f < 4; ++f) {
      bf16x8 bf = *(const bf16x8*)&Bs[(g * 64 + f * 16 + lane15) * 32 + quad * 8];
      acc[f] = MFMA16(af, bf, acc[f]);
    }
    #pragma unroll
    for (int f = 0; f < 4; ++f)
      #pragma unroll
      for (int rr = 0; rr < 4; ++rr)
        WR[2 + w * 16 + quad * 4 + rr][g * 64 + f * 16 + lane15] = acc[f][rr];
  }
  __syncthreads();

  // conv(K=3) + SiLU + rotate + L2 normalize; lane = d, wave x iter = t
  float cwa[3], cwb[3];
  #pragma unroll
  for (int i = 0; i < 3; ++i) {
    cwa[i] = conv_w[(long)(c0 + l) * 3 + i];
    cwb[i] = conv_w[(long)(c0 + 64 + l) * 3 + i];
  }
  float om = omega[r], ph = phi[r];
  for (int it = 0; it < 16; ++it) {
    int tl = it * 4 + w;
    int t = rm + tl;
    float a = cwa[0] * WR[tl][l] + cwa[1] * WR[tl + 1][l] + cwa[2] * WR[tl + 2][l];
    float b = cwb[0] * WR[tl][64 + l] + cwb[1] * WR[tl + 1][64 + l] + cwb[2] * WR[tl + 2][64 + l];
    a = a / (1.f + expf(-a));
    b = b / (1.f + expf(-b));
    float th = om * (float)t + ph;
    float wd = a * cosf(th) + b * sinf(th);
    float ss = wd * wd;
    #pragma unroll
    for (int o = 32; o > 0; o >>= 1) ss += __shfl_xor(ss, o, 64);
    whb[((long)p * TTD + t) * HDIM + l] = f2b(wd * (1.f / sqrtf(ss + 1e-6f)));
  }
}

// ---------------- solveA: Tbeta = (I+Lm)^-1 diag(beta), Yb = Tbeta.wh ----------------
__global__ __launch_bounds__(256) void solveA_kernel(
    const ushort* __restrict__ whb, const float* __restrict__ beta,
    ushort* __restrict__ TB, ushort* __restrict__ YB)
{
  int c = blockIdx.x, h = blockIdx.y;
  const ushort* whc = whb + ((long)h * TTD + c * 64) * HDIM;
  const float* bet = beta + (long)h * TTD + c * 64;
  ushort* TBh = TB + ((long)h * 16 + c) * 4096;
  ushort* YBh = YB + ((long)h * 16 + c) * 4096;

  __shared__ float Lm[64][65];
  __shared__ float Vf[64][65];
  __shared__ ushort WT[64 * LS];
  __shared__ ushort Tb[64 * LS];

  int tid = threadIdx.x, w = tid >> 6, l = tid & 63;
  int quad = l >> 4, lane15 = l & 15;

  f32x4 g[4] = {};
  #pragma unroll
  for (int s = 0; s < 2; ++s) {
    bf16x8 af = *(const bf16x8*)&whc[(long)(w * 16 + lane15) * HDIM + s * 32 + quad * 8];
    #pragma unroll
    for (int f = 0; f < 4; ++f) {
      bf16x8 bf = *(const bf16x8*)&whc[(long)(f * 16 + lane15) * HDIM + s * 32 + quad * 8];
      g[f] = MFMA16(af, bf, g[f]);
    }
  }
  #pragma unroll
  for (int r = 0; r < 4; ++r) {
    int t = w * 16 + quad * 4 + r;
    float bv = bet[t];
    #pragma unroll
    for (int f = 0; f < 4; ++f) {
      int tp = f * 16 + lane15;
      Lm[t][tp] = (t > tp) ? bv * g[f][r] : 0.f;
    }
  }
  {
    int d0 = (tid & 7) * 8;
    #pragma unroll
    for (int it = 0; it < 2; ++it) {
      int t = it * 32 + (tid >> 3);
      uint4 pk = *(const uint4*)&whc[(long)t * HDIM + d0];
      const ushort* pu = (const ushort*)&pk;
      #pragma unroll
      for (int i = 0; i < 8; ++i) WT[(d0 + i) * LS + t] = pu[i];
    }
  }
  __syncthreads();

  {
    float cur[16];
    #pragma unroll
    for (int i = 0; i < 16; ++i) cur[i] = (w * 16 + i == l) ? bet[l] : 0.f;
    for (int sb = 0; sb < 4; ++sb) {
      if (w == sb) {
        float xloc[16];
        #pragma unroll
        for (int i = 0; i < 16; ++i) {
          float bv = cur[i];
          #pragma unroll
          for (int j2 = 0; j2 < 16; ++j2)
            if (j2 < i) bv -= Lm[sb * 16 + i][sb * 16 + j2] * xloc[j2];
          xloc[i] = bv;
          Vf[sb * 16 + i][l] = bv;
        }
      }
      __syncthreads();
      if (w > sb) {
        float xp[16];
        #pragma unroll
        for (int t = 0; t < 16; ++t) xp[t] = Vf[sb * 16 + t][l];
        #pragma unroll
        for (int i = 0; i < 16; ++i) {
          float s2 = cur[i];
          #pragma unroll
          for (int t = 0; t < 16; ++t) s2 -= Lm[w * 16 + i][sb * 16 + t] * xp[t];
          cur[i] = s2;
        }
      }
    }
  }
  {
    int t = tid >> 2, off = (tid & 3) * 16;
    ushort tmp[16];
    #pragma unroll
    for (int i = 0; i < 16; ++i) { tmp[i] = f2b(Vf[t][off + i]); Tb[t * LS + off + i] = tmp[i]; }
    *(uint4*)&TBh[t * 64 + off] = *(const uint4*)&tmp[0];
    *(uint4*)&TBh[t * 64 + off + 8] = *(const uint4*)&tmp[8];
  }
  __syncthreads();
  f32x4 y[4] = {};
  #pragma unroll
  for (int s = 0; s < 2; ++s) {
    bf16x8 af = *(const bf16x8*)&Tb[(w * 16 + lane15) * LS + s * 32 + quad * 8];
    #pragma unroll
    for (int f = 0; f < 4; ++f) {
      bf16x8 bf = *(const bf16x8*)&WT[(f * 16 + lane15) * LS + s * 32 + quad * 8];
      y[f] = MFMA16(af, bf, y[f]);
    }
  }
  #pragma unroll
  for (int f = 0; f < 4; ++f)
    #pragma unroll
    for (int r = 0; r < 4; ++r)
      YBh[(long)(w * 16 + quad * 4 + r) * 64 + f * 16 + lane15] = f2b(y[f][r]);
}

// ---------------- solveB: chunk recurrence; all tiles XOR-swizzled; K staged once ----------------
__global__ __launch_bounds__(256) void solveB_kernel(
    const ushort* __restrict__ whb, const ushort* __restrict__ kb,
    const ushort* __restrict__ TB, const ushort* __restrict__ YB,
    ushort* __restrict__ Xb, ushort* __restrict__ KZ)
{
  int h = blockIdx.x;
  int ty = blockIdx.y;
  int js = (ty < 8) ? ty : (23 - ty);
  int j0 = js * 64;
  const ushort* wh_h = whb + (long)h * TTD * HDIM;
  const ushort* k_h = kb + (long)(h >> 1) * 64;
  ushort* X_h = Xb + (long)h * TTD * TTD;
  ushort* KZ_h = KZ + (long)h * 15 * TTD * HDIM;

  __shared__ ushort KT[4096];
  __shared__ ushort WT[4096];
  __shared__ ushort XM[4096];
  __shared__ ushort nS[4096];

  int tid = threadIdx.x, w = tid >> 6, l = tid & 63;
  int quad = l >> 4, lane15 = l & 15;
  f32x4 Sacc[4] = {}, Wacc[4] = {};

  stage_tile(k_h + (long)j0 * DDM, DDM, KT, w, l);

  float kreg[4][4];
  #pragma unroll
  for (int f = 0; f < 4; ++f)
    #pragma unroll
    for (int r = 0; r < 4; ++r)
      kreg[f][r] = b2f(k_h[(long)(j0 + w * 16 + quad * 4 + r) * DDM + f * 16 + lane15]);

  for (int c = js; c < 16; ++c) {
    const ushort* whc = wh_h + (long)c * 64 * HDIM;
    __syncthreads();
    {
      int d0 = (tid & 7) * 8;
      #pragma unroll
      for (int it = 0; it < 2; ++it) {
        int t = it * 32 + (tid >> 3);
        uint4 pk = *(const uint4*)&whc[(long)t * HDIM + d0];
        const ushort* pu = (const ushort*)&pk;
        #pragma unroll
        for (int i = 0; i < 8; ++i) WT[SWZE(d0 + i, t)] = pu[i];
      }
    }
    f32x4 xacc[4] = {};
    if (c == js) {
      f32x4 m[4] = {};
      #pragma unroll
      for (int s = 0; s < 2; ++s) {
        bf16x8 af = *(const bf16x8*)&whc[(long)(w * 16 + lane15) * HDIM + s * 32 + quad * 8];
        #pragma unroll
        for (int f = 0; f < 4; ++f)
          m[f] = MFMA16(af, frag(KT, f * 16 + lane15, s * 4 + quad), m[f]);
      }
      #pragma unroll
      for (int f = 0; f < 4; ++f)
        #pragma unroll
        for (int r = 0; r < 4; ++r) {
          int t = w * 16 + quad * 4 + r, j = f * 16 + lane15;
          XM[SWZE(j, t)] = (t > j) ? f2b(m[f][r]) : (ushort)0;
        }
      __syncthreads();
      const ushort* TBh = TB + ((long)h * 16 + c) * 4096;
      #pragma unroll
      for (int s = 0; s < 2; ++s) {
        bf16x8 af = *(const bf16x8*)&TBh[(long)(w * 16 + lane15) * 64 + s * 32 + quad * 8];
        #pragma unroll
        for (int f = 0; f < 4; ++f)
          xacc[f] = MFMA16(af, frag(XM, f * 16 + lane15, s * 4 + quad), xacc[f]);
      }
      __syncthreads();
    } else {
      const ushort* YBh = YB + ((long)h * 16 + c) * 4096;
      #pragma unroll
      for (int s = 0; s < 2; ++s) {
        bf16x8 af = *(const bf16x8*)&YBh[(long)(w * 16 + lane15) * 64 + s * 32 + quad * 8];
        #pragma unroll
        for (int f = 0; f < 4; ++f) {
          xacc[f] = MFMA16(af, frag(KT, f * 16 + lane15, s * 4 + quad), xacc[f]);
          xacc[f] = MFMA16(af, frag(nS, f * 16 + lane15, s * 4 + quad), xacc[f]);
        }
      }
    }
    #pragma unroll
    for (int f = 0; f < 4; ++f)
      #pragma unroll
      for (int r = 0; r < 4; ++r)
        XM[SWZE(f * 16 + lane15, w * 16 + quad * 4 + r)] = f2b(xacc[f][r]);
    __syncthreads();
    {
      int j = tid >> 2, c2 = (tid & 3) * 2;
      bf16x8 s0 = frag(XM, j, c2);
      bf16x8 s1 = frag(XM, j, c2 + 1);
      *(bf16x8*)&X_h[(long)(j0 + j) * TTD + c * 64 + c2 * 8] = s0;
      *(bf16x8*)&X_h[(long)(j0 + j) * TTD + c * 64 + c2 * 8 + 8] = s1;
    }
    if (c < 15) {
      #pragma unroll
      for (int s = 0; s < 2; ++s) {
        bf16x8 aw = frag(WT, w * 16 + lane15, s * 4 + quad);
        bf16x8 ax = frag(XM, w * 16 + lane15, s * 4 + quad);
        #pragma unroll
        for (int f = 0; f < 4; ++f) {
          Sacc[f] = MFMA16(aw, frag(XM, f * 16 + lane15, s * 4 + quad), Sacc[f]);
          Wacc[f] = MFMA16(ax, frag(WT, f * 16 + lane15, s * 4 + quad), Wacc[f]);
        }
      }
      ushort* pz = KZ_h + (long)c * TTD * HDIM;
      #pragma unroll
      for (int f = 0; f < 4; ++f)
        #pragma unroll
        for (int r = 0; r < 4; ++r)
          pz[(long)(j0 + w * 16 + quad * 4 + r) * 64 + f * 16 + lane15] =
              f2b(kreg[f][r] - Wacc[f][r]);
      #pragma unroll
      for (int f = 0; f < 4; ++f)
        #pragma unroll
        for (int r = 0; r < 4; ++r)
          nS[SWZE(f * 16 + lane15, w * 16 + quad * 4 + r)] = f2b(-Sacc[f][r]);
    }
  }
}

// ---------------- flash: one row tile/block, 2 blocks/CU, async dbuf {KZ,X,V} ----------------
__global__ __launch_bounds__(256) void flash_kernel(
    const ushort* __restrict__ qb, const ushort* __restrict__ kbuf,
    const ushort* __restrict__ whb, const ushort* __restrict__ Xb,
    const ushort* __restrict__ KZ, const ushort* __restrict__ vTb,
    ushort* __restrict__ oall)
{
  int h = blockIdx.x;
  int y = blockIdx.y;
  int ri = (y < 8) ? y : (23 - y);
  int r0 = ri * 64;
  const ushort* q_h = qb + (long)(h >> 1) * 64;
  const ushort* k_h = kbuf + (long)(h >> 1) * 64;
  const ushort* wh_h = whb + (long)h * TTD * HDIM;
  const ushort* X_h = Xb + (long)h * TTD * TTD;
  const ushort* kz = KZ + ((long)h * 15 + (ri - 1)) * TTD * HDIM;
  const ushort* v_h = vTb + (long)(h >> 1) * 64 * TTD;

  __shared__ ushort S[2][3][4096];
  __shared__ ushort KD[4096];
  __shared__ ushort QWD[4096];
  __shared__ ushort PT[4096];

  int tid = threadIdx.x, w = tid >> 6, l = tid & 63;
  int quad = l >> 4, lane15 = l & 15;

  bf16x8 aq[2];
  #pragma unroll
  for (int s = 0; s < 2; ++s)
    aq[s] = *(const bf16x8*)&q_h[(long)(r0 + w * 16 + lane15) * DDM + s * 32 + quad * 8];
  {
    f32x4 t4[4] = {};
    #pragma unroll
    for (int s = 0; s < 2; ++s)
      #pragma unroll
      for (int f = 0; f < 4; ++f) {
        bf16x8 bf = *(const bf16x8*)&wh_h[(long)(r0 + f * 16 + lane15) * HDIM + s * 32 + quad * 8];
        t4[f] = MFMA16(aq[s], bf, t4[f]);
      }
    #pragma unroll
    for (int f = 0; f < 4; ++f)
      #pragma unroll
      for (int r = 0; r < 4; ++r) {
        int i = w * 16 + quad * 4 + r, t = f * 16 + lane15;
        QWD[SWZE(i, t)] = (i >= t) ? f2b(-t4[f][r]) : (ushort)0;
      }
  }
  stage_tile(k_h + (long)r0 * DDM, DDM, KD, w, l);
  if (ri > 0) stage_tile(kz, 64, &S[0][0][0], w, l);
  stage_tile(X_h + r0, TTD, &S[0][1][0], w, l);
  stage_tile(v_h, TTD, &S[0][2][0], w, l);
  __syncthreads();

  f32x4 O[4] = {};
  float m[4], lsum[4];
  #pragma unroll
  for (int r = 0; r < 4; ++r) { m[r] = -1e30f; lsum[r] = 0.f; }

  int cur = 0;
  for (int jb = 0; jb <= ri; ++jb) {
    if (jb < ri) {
      long c0n = (long)(jb + 1) * 64;
      ushort* nb = &S[cur ^ 1][0][0];
      if (jb + 1 < ri) stage_tile(kz + c0n * 64, 64, nb, w, l);
      stage_tile(X_h + c0n * TTD + r0, TTD, nb + 4096, w, l);
      stage_tile(v_h + c0n, TTD, nb + 8192, w, l);
    }
    const ushort* Skz = &S[cur][0][0];
    const ushort* Sx  = &S[cur][1][0];
    const ushort* Sv  = &S[cur][2][0];
    f32x4 acc[4] = {};
    const ushort* Sb = (jb < ri) ? Skz : KD;
    #pragma unroll
    for (int s = 0; s < 2; ++s)
      #pragma unroll
      for (int f = 0; f < 4; ++f)
        acc[f] = MFMA16(aq[s], frag(Sb, f * 16 + lane15, s * 4 + quad), acc[f]);
    #pragma unroll
    for (int s = 0; s < 2; ++s) {
      bf16x8 aw = frag(QWD, w * 16 + lane15, s * 4 + quad);
      #pragma unroll
      for (int f = 0; f < 4; ++f)
        acc[f] = MFMA16(aw, frag(Sx, f * 16 + lane15, s * 4 + quad), acc[f]);
    }
    float rmax[4] = {-3e38f, -3e38f, -3e38f, -3e38f};
    #pragma unroll
    for (int f = 0; f < 4; ++f)
      #pragma unroll
      for (int r = 0; r < 4; ++r) {
        float lv = acc[f][r] * PSCALE;
        if (jb == ri && (f * 16 + lane15) > (w * 16 + quad * 4 + r)) lv = -3e38f;
        acc[f][r] = lv;
        rmax[r] = fmaxf(rmax[r], lv);
      }
    #pragma unroll
    for (int r = 0; r < 4; ++r) {
      rmax[r] = fmaxf(rmax[r], __shfl_xor(rmax[r], 1, 64));
      rmax[r] = fmaxf(rmax[r], __shfl_xor(rmax[r], 2, 64));
      rmax[r] = fmaxf(rmax[r], __shfl_xor(rmax[r], 4, 64));
      rmax[r] = fmaxf(rmax[r], __shfl_xor(rmax[r], 8, 64));
    }
    float alpha[4], rs[4] = {0.f, 0.f, 0.f, 0.f};
    #pragma unroll
    for (int r = 0; r < 4; ++r) {
      float nm = fmaxf(m[r], rmax[r]);
      alpha[r] = __expf(m[r] - nm);
      m[r] = nm;
    }
    #pragma unroll
    for (int f = 0; f < 4; ++f)
      #pragma unroll
      for (int r = 0; r < 4; ++r) {
        float e = __expf(acc[f][r] - m[r]);
        acc[f][r] = e;
        rs[r] += e;
      }
    #pragma unroll
    for (int r = 0; r < 4; ++r) {
      rs[r] += __shfl_xor(rs[r], 1, 64);
      rs[r] += __shfl_xor(rs[r], 2, 64);
      rs[r] += __shfl_xor(rs[r], 4, 64);
      rs[r] += __shfl_xor(rs[r], 8, 64);
      lsum[r] = lsum[r] * alpha[r] + rs[r];
    }
    #pragma unroll
    for (int f = 0; f < 4; ++f)
      #pragma unroll
      for (int r = 0; r < 4; ++r) O[f][r] *= alpha[r];
    #pragma unroll
    for (int f = 0; f < 4; ++f)
      #pragma unroll
      for (int r = 0; r < 4; ++r) {
        int i = w * 16 + quad * 4 + r;
        PT[SWZE(i, f * 16 + lane15)] = f2b(acc[f][r]);
      }
    __syncthreads();
    #pragma unroll
    for (int s = 0; s < 2; ++s) {
      bf16x8 ap = frag(PT, w * 16 + lane15, s * 4 + quad);
      #pragma unroll
      for (int f = 0; f < 4; ++f)
        O[f] = MFMA16(ap, frag(Sv, f * 16 + lane15, s * 4 + quad), O[f]);
    }
    __syncthreads();
    cur ^= 1;
  }
  #pragma unroll
  for (int r = 0; r < 4; ++r) lsum[r] = 1.f / lsum[r];
  #pragma unroll
  for (int f = 0; f < 4; ++f)
    #pragma unroll
    for (int r = 0; r < 4; ++r)
      oall[(long)(r0 + w * 16 + quad * 4 + r) * 2048 + h * 64 + f * 16 + lane15] =
          f2b(O[f][r] * lsum[r]);
}

// ---------------- final GEMM: out = o_all(bf16) @ ow_b^T (async dbuf swizzled) ----------------
__global__ __launch_bounds__(256) void gemm_out_kernel(
    const ushort* __restrict__ A, const ushort* __restrict__ Bb, float* __restrict__ C)
{
  __shared__ ushort Ab[2][4096];
  __shared__ ushort Bt[2][4096];
  int tid = threadIdx.x, w = tid >> 6, l = tid & 63;
  int quad = l >> 4, lane15 = l & 15;
  int rm = blockIdx.y * 64, cn = blockIdx.x * 64;
  const ushort* Ag = A + (long)rm * 2048;
  const ushort* Bg = Bb + (long)cn * 2048;

  stage_tile(Ag, 2048, &Ab[0][0], w, l);
  stage_tile(Bg, 2048, &Bt[0][0], w, l);
  __syncthreads();

  f32x4 acc[4] = {};
  int cur = 0;
  for (int kt = 0; kt < 32; ++kt) {
    if (kt < 31) {
      stage_tile(Ag + (kt + 1) * 64, 2048, &Ab[cur ^ 1][0], w, l);
      stage_tile(Bg + (kt + 1) * 64, 2048, &Bt[cur ^ 1][0], w, l);
    }
    #pragma unroll
    for (int s = 0; s < 2; ++s) {
      bf16x8 af = frag(&Ab[cur][0], w * 16 + lane15, s * 4 + quad);
      #pragma unroll
      for (int f = 0; f < 4; ++f)
        acc[f] = MFMA16(af, frag(&Bt[cur][0], f * 16 + lane15, s * 4 + quad), acc[f]);
    }
    __syncthreads();
    cur ^= 1;
  }
  int orow = rm + w * 16 + quad * 4;
  #pragma unroll
  for (int f = 0; f < 4; ++f)
    #pragma unroll
    for (int r = 0; r < 4; ++r)
      C[(long)(orow + r) * DDM + cn + f * 16 + lane15] = acc[f][r];
}

// ---------------- host ----------------
extern "C" void kernel_launch(void* const* d_in, const int* in_sizes, int n_in,
                              void* d_out, int out_size, void* d_ws, size_t ws_size,
                              hipStream_t stream) {
  const float* hs     = (const float*)d_in[0];
  const float* q_w    = (const float*)d_in[1];
  const float* k_w    = (const float*)d_in[2];
  const float* v_w    = (const float*)d_in[3];
  const float* w1     = (const float*)d_in[4];
  const float* w2     = (const float*)d_in[5];
  const float* conv_w = (const float*)d_in[6];
  const float* bt_w   = (const float*)d_in[7];
  const float* bt_b   = (const float*)d_in[8];
  const float* o_w    = (const float*)d_in[9];
  const float* omega  = (const float*)d_in[10];
  const float* phi    = (const float*)d_in[11];
  float* out = (float*)d_out;
  char* ws = (char*)d_ws;

  ushort* Xb     = (ushort*)(ws + OFF_X);
  ushort* KZb    = (ushort*)(ws + OFF_PZ);
  ushort* hs_b   = (ushort*)(ws + OFF_HSB);
  ushort* qw_wb  = (ushort*)(ws + OFF_QWW);
  ushort* kw_wb  = (ushort*)(ws + OFF_KWW);
  ushort* vw_wb  = (ushort*)(ws + OFF_VWW);
  ushort* w2_b   = (ushort*)(ws + OFF_W2B);
  ushort* wlow_b = (ushort*)(ws + OFF_WLOWB);
  ushort* TB     = (ushort*)(ws + OFF_TB);
  ushort* o_all  = (ushort*)(ws + OFF_OALL);
  ushort* YB     = (ushort*)(ws + OFF_YB);
  ushort* ow_b   = (ushort*)(ws + OFF_OWB);
  ushort* wh_b   = (ushort*)(ws + OFF_WHB);
  ushort* q_b    = (ushort*)(ws + OFF_QB);
  ushort* k_b    = (ushort*)(ws + OFF_KB);
  ushort* vT_b   = (ushort*)(ws + OFF_VTB);
  float*  beta   = (float*)(ws + OFF_BETA);
  ushort* bw_b   = (ushort*)(ws + OFF_BW64);

  CvtSegs sg;
  sg.src[0] = hs;   sg.dst[0] = hs_b;          sg.cnt[0] = 1048576;
  sg.src[1] = q_w;  sg.dst[1] = qw_wb;         sg.cnt[1] = 1048576;
  sg.src[2] = k_w;  sg.dst[2] = kw_wb;         sg.cnt[2] = 1048576;
  sg.src[3] = v_w;  sg.dst[3] = vw_wb;         sg.cnt[3] = 1048576;
  sg.src[4] = w2;   sg.dst[4] = w2_b;          sg.cnt[4] = 131072;
  sg.src[5] = bt_w; sg.dst[5] = bw_b;          sg.cnt[5] = 32768;
  cvt_all_kernel<<<dim3((CVT_TOTAL + 1023) / 1024), 256, 0, stream>>>(sg);
  cvt_kernel<<<dim3(32), 256, 0, stream>>>(w1, bw_b + 32768, 32768L);

  // QKV + small projections (beta, w_low) in one launch
  qkv_sp_kernel<<<dim3(16, 16, 4), 256, 0, stream>>>(
      hs_b, qw_wb, kw_wb, vw_wb, bw_b, bt_b, q_b, k_b, vT_b, beta, wlow_b);

  // fused w_raw GEMM + conv + SiLU + rotate + normalize -> wh
  wrawconv_kernel<<<dim3(16, 32), 256, 0, stream>>>(
      wlow_b, w2_b, conv_w, omega, phi, wh_b);

  solveA_kernel<<<dim3(16, 32), 256, 0, stream>>>(wh_b, beta, TB, YB);
  solveB_kernel<<<dim3(32, 16), 256, 0, stream>>>(wh_b, k_b, TB, YB, Xb, KZb);

  // o_w -> bf16 into YB region (dead after solveB)
  cvt_kernel<<<dim3(2048), 256, 0, stream>>>(o_w, ow_b, 2097152L);

  flash_kernel<<<dim3(32, 16), 256, 0, stream>>>(q_b, k_b, wh_b, Xb, KZb, vT_b, o_all);

  gemm_out_kernel<<<dim3(16, 16), 256, 0, stream>>>(o_all, ow_b, out);

  (void)in_sizes; (void)n_in; (void)out_size; (void)ws_size;
}